// Round 5
// baseline (639.110 us; speedup 1.0000x reference)
//
#include <hip/hip_runtime.h>
#include <hip/hip_bf16.h>
#include <stdint.h>

#define CDIM 256
#define HH 36
#define WW 36
#define NPX 1296          // 36*36
#define PW 38             // padded width (1-px halo)
#define PPIX 1444         // 38*38
#define NIMG 32
#define NROI 512
#define FCK 4096
#define EPS_BN 1e-5f
#define NSLOT 704         // partial-stat slots per cot half: 352 blocks x 2 px-wave halves

typedef __bf16 bf16;
typedef __bf16 bf16x8 __attribute__((ext_vector_type(8)));
typedef float f32x4 __attribute__((ext_vector_type(4)));
typedef unsigned short us8 __attribute__((ext_vector_type(8)));

// async global->LDS, 16B per lane; LDS dest is wave-uniform base + lane*16
#define GLD16(g, l) __builtin_amdgcn_global_load_lds( \
    (__attribute__((address_space(1))) void*)(g),     \
    (__attribute__((address_space(3))) void*)(l), 16, 0, 0)

// ---------------- weight reorder (all 3 layers): w[co][ci][3][3] f32 -> wb[l][tap][co][ci] bf16
__global__ void k_wconv3(const float* __restrict__ w0, const float* __restrict__ w1,
                         const float* __restrict__ w2, bf16* __restrict__ wb) {
  int l = blockIdx.y;
  const float* ws = (l == 0) ? w0 : (l == 1) ? w1 : w2;
  bf16* dst = wb + (size_t)l * 9 * CDIM * CDIM;
  int i = blockIdx.x * 256 + threadIdx.x;
  if (i >= 9 * CDIM * CDIM) return;
  int tap = i / (CDIM * CDIM);
  int rem = i - tap * (CDIM * CDIM);
  int co = rem >> 8, ci = rem & 255;
  dst[i] = (bf16)ws[(size_t)(co * CDIM + ci) * 9 + tap];
}

// ---------------- generic f32 -> bf16 cast
__global__ void k_cast(const float* __restrict__ src, bf16* __restrict__ dst, int nElem) {
  int i = blockIdx.x * 256 + threadIdx.x;
  if (i < nElem) dst[i] = (bf16)src[i];
}

// ---------------- feat NCHW f32 -> padded NHWC bf16 via LDS transpose
__global__ void k_convert(const float* __restrict__ feat, bf16* __restrict__ xp) {
  __shared__ bf16 tile[CDIM * 38];
  int h = blockIdx.x, n = blockIdx.y, t = threadIdx.x;
  const float* src = feat + (size_t)n * CDIM * NPX + (size_t)h * WW;
#pragma unroll 4
  for (int i = 0; i < 36; ++i) {
    int f = i * 256 + t;
    int c = (int)(((unsigned)f * 7282u) >> 18);  // f/36
    int w = f - c * 36;
    tile[c * 38 + w] = (bf16)src[(size_t)c * NPX + w];
  }
  __syncthreads();
  bf16* dst = xp + (size_t)n * PPIX * CDIM + ((h + 1) * PW + 1) * CDIM + t;
#pragma unroll 4
  for (int w = 0; w < 36; ++w) dst[w * CDIM] = tile[t * 38 + w];
}

// ---------------- conv3x3 implicit GEMM, 128co x 128px tile, bf16 MFMA
// Round-1 grid (11,2,NIMG): z-major dispatch -> natural image temporal locality.
// Fused BN partial stats (non-atomic); bf16 NHWC out.
__global__ __launch_bounds__(256) void k_conv(
    const bf16* __restrict__ xp, const bf16* __restrict__ wb,
    bf16* __restrict__ y, float* __restrict__ psum, float* __restrict__ psq)
{
  __shared__ __align__(16) bf16 ldsA[2][4096];
  __shared__ __align__(16) bf16 ldsB[2][4096];
  const int tid = threadIdx.x;
  const int wave = tid >> 6, lane = tid & 63;
  const int pxt = blockIdx.x, cot = blockIdx.y, n = blockIdx.z;

  // staging addressing (XOR chunk swizzle pre-applied to global source)
  const int q = lane >> 2;
  const int gsw = (lane & 3) ^ ((q >> 1) & 3);
  const int rA = wave * 32 + q;
  const bf16* aS0 = wb + (size_t)(cot * 128 + rA) * CDIM + gsw * 8;
  const bf16* aS1 = aS0 + 16 * CDIM;
  int pxa = pxt * 128 + rA;       if (pxa > NPX - 1) pxa = NPX - 1;
  int pxb = pxt * 128 + rA + 16;  if (pxb > NPX - 1) pxb = NPX - 1;
  const int ha = pxa / 36, wa = pxa - ha * 36;
  const int hb = pxb / 36, wbv = pxb - hb * 36;
  const bf16* bS0 = xp + (size_t)n * (PPIX * CDIM) + ((ha + 1) * PW + (wa + 1)) * CDIM + gsw * 8;
  const bf16* bS1 = xp + (size_t)n * (PPIX * CDIM) + ((hb + 1) * PW + (wbv + 1)) * CDIM + gsw * 8;

  // fragment-read addressing
  const int fr = lane & 15, fg = lane >> 4;
  const int fsw = (fg ^ ((fr >> 1) & 3)) * 8;
  const int wco = wave >> 1, wpx = wave & 1;
  const int aoff = (wco * 64 + fr) * 32 + fsw;
  const int boff = (wpx * 64 + fr) * 32 + fsw;

  f32x4 acc[4][4];
#pragma unroll
  for (int i = 0; i < 4; ++i)
#pragma unroll
    for (int j = 0; j < 4; ++j) acc[i][j] = f32x4{0.f, 0.f, 0.f, 0.f};

  { // prologue: stage k=0 (tap 0: dh=-1,dw=-1, ci0=0)
    const int xoff = -(PW + 1) * CDIM;
    GLD16(aS0, &ldsA[0][wave * 1024]);
    GLD16(aS1, &ldsA[0][wave * 1024 + 512]);
    GLD16(bS0 + xoff, &ldsB[0][wave * 1024]);
    GLD16(bS1 + xoff, &ldsB[0][wave * 1024 + 512]);
  }

#pragma unroll 2
  for (int k = 0; k < 72; ++k) {
    const int buf = k & 1;
    __syncthreads();
    if (k + 1 < 72) {
      const int kn = k + 1;
      const int tap = kn >> 3, ci0 = (kn & 7) << 5;
      const int dh = tap / 3 - 1, dw = tap - (tap / 3) * 3 - 1;
      const int woff = tap * (CDIM * CDIM) + ci0;
      const int xoff = (dh * PW + dw) * CDIM + ci0;
      const int nb = buf ^ 1;
      GLD16(aS0 + woff, &ldsA[nb][wave * 1024]);
      GLD16(aS1 + woff, &ldsA[nb][wave * 1024 + 512]);
      GLD16(bS0 + xoff, &ldsB[nb][wave * 1024]);
      GLD16(bS1 + xoff, &ldsB[nb][wave * 1024 + 512]);
    }
    bf16x8 av[4], bv[4];
#pragma unroll
    for (int i = 0; i < 4; ++i) av[i] = *(const bf16x8*)&ldsA[buf][aoff + i * 512];
#pragma unroll
    for (int j = 0; j < 4; ++j) bv[j] = *(const bf16x8*)&ldsB[buf][boff + j * 512];
#pragma unroll
    for (int i = 0; i < 4; ++i)
#pragma unroll
      for (int j = 0; j < 4; ++j)
        acc[i][j] = __builtin_amdgcn_mfma_f32_16x16x32_bf16(av[i], bv[j], acc[i][j], 0, 0, 0);
  }

  // epilogue: C/D layout col(px)=lane&15, row(co)=(lane>>4)*4+reg
  float ssum[16], ssq2[16];
#pragma unroll
  for (int u = 0; u < 16; ++u) { ssum[u] = 0.f; ssq2[u] = 0.f; }
#pragma unroll
  for (int j = 0; j < 4; ++j) {
    const int px = pxt * 128 + wpx * 64 + j * 16 + fr;
    if (px < NPX) {
      bf16* dst = y + ((size_t)n * NPX + px) * CDIM + cot * 128 + wco * 64 + fg * 4;
#pragma unroll
      for (int i = 0; i < 4; ++i) {
        f32x4 a = acc[i][j];
        union { bf16 b4[4]; ushort4 u4; } pk;
        pk.b4[0] = (bf16)a[0]; pk.b4[1] = (bf16)a[1];
        pk.b4[2] = (bf16)a[2]; pk.b4[3] = (bf16)a[3];
        *(ushort4*)(dst + i * 16) = pk.u4;
#pragma unroll
        for (int r = 0; r < 4; ++r) {
          float v = a[r];
          ssum[i * 4 + r] += v; ssq2[i * 4 + r] += v * v;
        }
      }
    }
  }
  // reduce over the 16 px-lanes (fr) of each fg group
#pragma unroll
  for (int m = 1; m < 16; m <<= 1)
#pragma unroll
    for (int u = 0; u < 16; ++u) {
      ssum[u] += __shfl_xor(ssum[u], m);
      ssq2[u] += __shfl_xor(ssq2[u], m);
    }
  // non-atomic partial store: slot = cot*704 + (n*11+pxt)*2 + wpx, 128 ch per slot
  if (fr == 0) {
    const size_t slot = (size_t)cot * NSLOT + (n * 11 + pxt) * 2 + wpx;
    float* ps = psum + slot * 128 + wco * 64 + fg * 4;
    float* pq = psq  + slot * 128 + wco * 64 + fg * 4;
#pragma unroll
    for (int qq = 0; qq < 4; ++qq) {
      f32x4 vs = f32x4{ssum[qq*4+0], ssum[qq*4+1], ssum[qq*4+2], ssum[qq*4+3]};
      f32x4 vq = f32x4{ssq2[qq*4+0], ssq2[qq*4+1], ssq2[qq*4+2], ssq2[qq*4+3]};
      *(f32x4*)(ps + qq * 16) = vs;
      *(f32x4*)(pq + qq * 16) = vq;
    }
  }
}

// ---------------- partial-stat reduction: 16 blocks, each sums 44 slots -> 16 atomics/ch
__global__ void k_partred(const float* __restrict__ psum, const float* __restrict__ psq,
                          float* __restrict__ su, float* __restrict__ sq) {
  int c = threadIdx.x;              // global channel
  int cot = c >> 7, lcl = c & 127;
  int i0 = blockIdx.x * (NSLOT / 16);
  const float* ps = psum + ((size_t)cot * NSLOT + i0) * 128 + lcl;
  const float* pq = psq  + ((size_t)cot * NSLOT + i0) * 128 + lcl;
  float s = 0.f, s2 = 0.f;
  for (int i = 0; i < NSLOT / 16; ++i) { s += ps[i * 128]; s2 += pq[i * 128]; }
  atomicAdd(&su[c], s);
  atomicAdd(&sq[c], s2);
}

// ---------------- per-channel sum/sumsq over rows of a [rows][256] f32 array (fc only)
__global__ void k_stats(const float* __restrict__ x, float* __restrict__ sum,
                        float* __restrict__ ssq, int rpb) {
  int c = threadIdx.x;
  size_t base = (size_t)blockIdx.x * rpb;
  float s = 0.f, s2 = 0.f;
  for (int i = 0; i < rpb; ++i) {
    float v = x[(base + i) * CDIM + c];
    s += v; s2 += v * v;
  }
  atomicAdd(&sum[c], s);
  atomicAdd(&ssq[c], s2);
}

__global__ void k_finalize(const float* __restrict__ sum, const float* __restrict__ ssq,
                           const float* __restrict__ g, const float* __restrict__ b,
                           float* __restrict__ sc, float* __restrict__ sh, float invn) {
  int c = threadIdx.x;
  float m = sum[c] * invn;
  float v = ssq[c] * invn - m * m;
  float s = g[c] * rsqrtf(v + EPS_BN);
  sc[c] = s;
  sh[c] = b[c] - m * s;
}

// ---------------- y bf16 NHWC -> BN+ReLU -> padded NHWC bf16 (interior only)
__global__ void k_normalize(const bf16* __restrict__ y, const float* __restrict__ sc,
                            const float* __restrict__ sh, bf16* __restrict__ xp) {
  int t = threadIdx.x;
  int n = blockIdx.y;
  int px = blockIdx.x * 8 + (t >> 5);
  int c8 = (t & 31) * 8;
  const bf16* srcp = y + ((size_t)n * NPX + px) * CDIM + c8;
  union { bf16 b8[8]; us8 u; } in, outp;
  in.u = *(const us8*)srcp;
  int h = px / 36, w = px - h * 36;
#pragma unroll
  for (int i = 0; i < 8; ++i) {
    float v = (float)in.b8[i];
    outp.b8[i] = (bf16)fmaxf(v * sc[c8 + i] + sh[c8 + i], 0.f);
  }
  *(us8*)(xp + (size_t)n * PPIX * CDIM + ((h + 1) * PW + (w + 1)) * CDIM + c8) = outp.u;
}

// ---------------- trapezoid cumsum along W (Ux), inline BN+ReLU of y
__global__ void k_p1(const bf16* __restrict__ y, const float* __restrict__ sc,
                     const float* __restrict__ sh, float* __restrict__ Ux) {
  int c = threadIdx.x, h = blockIdx.x, n = blockIdx.y;
  const bf16* row = y + ((size_t)n * NPX + h * WW) * CDIM + c;
  float* orow = Ux + ((size_t)n * NPX + h * WW) * CDIM + c;
  float s = sc[c], t = sh[c];
  float prev = fmaxf((float)row[0] * s + t, 0.f);
  float run = 0.f;
  orow[0] = 0.f;
  for (int w = 1; w < WW; ++w) {
    float cur = fmaxf((float)row[w * CDIM] * s + t, 0.f);
    run += 0.5f * (prev + cur);
    orow[w * CDIM] = run;
    prev = cur;
  }
}

// ---------------- trapezoid cumsum along H: Uy (of x3) and T (of Ux)
__global__ void k_p2(const bf16* __restrict__ y, const float* __restrict__ sc,
                     const float* __restrict__ sh, const float* __restrict__ Ux,
                     float* __restrict__ Uy, float* __restrict__ T) {
  int c = threadIdx.x, w = blockIdx.x, n = blockIdx.y;
  size_t base = (size_t)n * NPX * CDIM + (size_t)w * CDIM + c;
  float s = sc[c], t = sh[c];
  float prevF = fmaxf((float)y[base] * s + t, 0.f);
  float prevU = Ux[base];
  float runF = 0.f, runU = 0.f;
  Uy[base] = 0.f; T[base] = 0.f;
  for (int h = 1; h < HH; ++h) {
    size_t idx = base + (size_t)h * WW * CDIM;
    float f = fmaxf((float)y[idx] * s + t, 0.f);
    float u = Ux[idx];
    runF += 0.5f * (prevF + f);
    runU += 0.5f * (prevU + u);
    Uy[idx] = runF; T[idx] = runU;
    prevF = f; prevU = u;
  }
}

// ---------------- PrRoI pool: one block per roi, thread=channel; rf[roi][c*16+i*4+j] bf16
__global__ void k_pool(const bf16* __restrict__ y, const float* __restrict__ sc,
                       const float* __restrict__ sh, const float* __restrict__ Ux,
                       const float* __restrict__ Uy, const float* __restrict__ T,
                       const float* __restrict__ props, bf16* __restrict__ rf) {
  int roi = blockIdx.x, c = threadIdx.x;
  int b = roi >> 4;
  const float* pr = props + (size_t)roi * 4;
  float x1 = pr[0] * 20.f, yy1 = pr[1] * 20.f;
  float x2 = (pr[0] + pr[2]) * 20.f, yy2 = (pr[1] + pr[3]) * 20.f;
  float bw = (x2 - x1) * 0.25f, bh = (yy2 - yy1) * 0.25f;
  float px0a[5], px1a[5], py0a[5], py1a[5];
  int wx[5], hy[5];
#pragma unroll
  for (int j = 0; j < 5; ++j) {
    float xs = fminf(fmaxf(x1 + bw * j, 0.f), 35.f);
    int wi = (int)floorf(xs); wi = wi < 0 ? 0 : (wi > 34 ? 34 : wi);
    float sx = xs - (float)wi;
    float p1 = 0.5f * sx * sx;
    wx[j] = wi; px1a[j] = p1; px0a[j] = sx - p1;
    float ys = fminf(fmaxf(yy1 + bh * j, 0.f), 35.f);
    int hi = (int)floorf(ys); hi = hi < 0 ? 0 : (hi > 34 ? 34 : hi);
    float sy = ys - (float)hi;
    float q1 = 0.5f * sy * sy;
    hy[j] = hi; py1a[j] = q1; py0a[j] = sy - q1;
  }
  float s = sc[c], tt = sh[c];
  const size_t nb = (size_t)b * NPX * CDIM + c;
  float G[5][5];
#pragma unroll
  for (int i = 0; i < 5; ++i) {
    int h0 = hy[i], h1 = h0 + 1;
#pragma unroll
    for (int j = 0; j < 5; ++j) {
      int w0 = wx[j], w1 = w0 + 1;
      size_t i00 = nb + (size_t)(h0 * WW + w0) * CDIM;
      size_t i01 = nb + (size_t)(h0 * WW + w1) * CDIM;
      size_t i10 = nb + (size_t)(h1 * WW + w0) * CDIM;
      size_t i11 = nb + (size_t)(h1 * WW + w1) * CDIM;
      float f00 = fmaxf((float)y[i00] * s + tt, 0.f);
      float f01 = fmaxf((float)y[i01] * s + tt, 0.f);
      float f10 = fmaxf((float)y[i10] * s + tt, 0.f);
      float f11 = fmaxf((float)y[i11] * s + tt, 0.f);
      G[i][j] = T[i00] + Uy[i00] * px0a[j] + Uy[i01] * px1a[j]
              + py0a[i] * (Ux[i00] + f00 * px0a[j] + f01 * px1a[j])
              + py1a[i] * (Ux[i10] + f10 * px0a[j] + f11 * px1a[j]);
    }
  }
  float area = bw * bh;
  float inv = area > 1e-8f ? 1.f / area : 0.f;
  bf16 outv[16];
#pragma unroll
  for (int i = 0; i < 4; ++i)
#pragma unroll
    for (int j = 0; j < 4; ++j) {
      float d = G[i + 1][j + 1] - G[i][j + 1] - G[i + 1][j] + G[i][j];
      outv[i * 4 + j] = (bf16)(d * inv);
    }
  bf16* dst = rf + (size_t)roi * FCK + c * 16;
  *(us8*)(dst)     = *(us8*)&outv[0];
  *(us8*)(dst + 8) = *(us8*)&outv[8];
}

// ---------------- fc GEMM: fcp[ks][roi][o] = partial, split-K=8, MFMA, no atomics
__global__ __launch_bounds__(256) void k_fcgemm(const bf16* __restrict__ rf,
                                                const bf16* __restrict__ fw,
                                                float* __restrict__ fcp) {
  int tid = threadIdx.x, wave = tid >> 6, lane = tid & 63;
  int wo = wave >> 1, wr = wave & 1;
  int rt = blockIdx.x, ot = blockIdx.y, ks = blockIdx.z;
  int fr = lane & 15, fg = lane >> 4;
  const bf16* ap = fw + (size_t)(ot * 64 + wo * 32 + fr) * FCK + ks * 512 + fg * 8;
  const bf16* bp = rf + (size_t)(rt * 64 + wr * 32 + fr) * FCK + ks * 512 + fg * 8;
  f32x4 acc[2][2];
#pragma unroll
  for (int i = 0; i < 2; ++i)
#pragma unroll
    for (int j = 0; j < 2; ++j) acc[i][j] = f32x4{0.f, 0.f, 0.f, 0.f};
#pragma unroll 4
  for (int k = 0; k < 512; k += 32) {
    bf16x8 a0 = *(const bf16x8*)(ap + k);
    bf16x8 a1 = *(const bf16x8*)(ap + 16 * FCK + k);
    bf16x8 b0 = *(const bf16x8*)(bp + k);
    bf16x8 b1 = *(const bf16x8*)(bp + 16 * FCK + k);
    acc[0][0] = __builtin_amdgcn_mfma_f32_16x16x32_bf16(a0, b0, acc[0][0], 0, 0, 0);
    acc[0][1] = __builtin_amdgcn_mfma_f32_16x16x32_bf16(a0, b1, acc[0][1], 0, 0, 0);
    acc[1][0] = __builtin_amdgcn_mfma_f32_16x16x32_bf16(a1, b0, acc[1][0], 0, 0, 0);
    acc[1][1] = __builtin_amdgcn_mfma_f32_16x16x32_bf16(a1, b1, acc[1][1], 0, 0, 0);
  }
#pragma unroll
  for (int i = 0; i < 2; ++i)
#pragma unroll
    for (int j = 0; j < 2; ++j) {
      int o = ot * 64 + wo * 32 + i * 16 + fg * 4;
      int r = rt * 64 + wr * 32 + j * 16 + fr;
      *(f32x4*)(fcp + ((size_t)ks * NROI + r) * CDIM + o) = acc[i][j];
    }
}

// ---------------- reduce split-K slabs: fcx[r][o] = sum_ks fcp[ks][r][o]
__global__ void k_fcred(const float* __restrict__ fcp, float* __restrict__ fcx) {
  int r = blockIdx.x, o = threadIdx.x;
  float s = 0.f;
#pragma unroll
  for (int ks = 0; ks < 8; ++ks) s += fcp[((size_t)ks * NROI + r) * CDIM + o];
  fcx[(size_t)r * CDIM + o] = s;
}

// ---------------- fc BN + ReLU + iou head
__global__ void k_iou(const float* __restrict__ fcx, const float* __restrict__ sc,
                      const float* __restrict__ sh, const float* __restrict__ iw,
                      const float* __restrict__ ib, float* __restrict__ out) {
  __shared__ float red[4];
  int roi = blockIdx.x, t = threadIdx.x;
  float v = fcx[(size_t)roi * CDIM + t];
  v = fmaxf(v * sc[t] + sh[t], 0.f) * iw[t];
#pragma unroll
  for (int o = 32; o > 0; o >>= 1) v += __shfl_down(v, o);
  if ((t & 63) == 0) red[t >> 6] = v;
  __syncthreads();
  if (t == 0) out[roi] = red[0] + red[1] + red[2] + red[3] + ib[0];
}

extern "C" void kernel_launch(void* const* d_in, const int* in_sizes, int n_in,
                              void* d_out, int out_size, void* d_ws, size_t ws_size,
                              hipStream_t stream) {
  (void)in_sizes; (void)n_in; (void)out_size;
  const float* feat  = (const float*)d_in[0];
  const float* props = (const float*)d_in[1];
  const float* convw[3] = {(const float*)d_in[2], (const float*)d_in[6], (const float*)d_in[10]};
  const float* bng[3]   = {(const float*)d_in[4], (const float*)d_in[8], (const float*)d_in[12]};
  const float* bnb[3]   = {(const float*)d_in[5], (const float*)d_in[9], (const float*)d_in[13]};
  const float* fcw  = (const float*)d_in[14];
  const float* fcg  = (const float*)d_in[16];
  const float* fcbb = (const float*)d_in[17];
  const float* iw   = (const float*)d_in[18];
  const float* ib   = (const float*)d_in[19];
  float* out = (float*)d_out;

  char* w = (char*)d_ws;
  size_t off = 0;
  auto take = [&](size_t sz) -> char* { char* p = w + off; off += (sz + 255) & ~(size_t)255; return p; };
  const size_t SZ_XP = (size_t)NIMG * PPIX * CDIM * 2;
  const size_t SZ_YB = (size_t)NIMG * NPX * CDIM * 2;   // bf16 y
  const size_t SZ_U  = (size_t)NIMG * NPX * CDIM * 4;   // f32 integrals
  const size_t SZ_P  = (size_t)2 * NSLOT * 128 * 4;     // partial stats (one array)
  bf16*  xp0 = (bf16*)take(SZ_XP);
  bf16*  xp1 = (bf16*)take(SZ_XP);
  bf16*  y   = (bf16*)take(SZ_YB);
  float* Ux  = (float*)take(SZ_U);
  float* Uy  = (float*)take(SZ_U);
  float* Tt  = (float*)take(SZ_U);
  bf16*  wball = (bf16*)take((size_t)3 * 9 * CDIM * CDIM * 2);
  bf16*  fwb = (bf16*)take((size_t)CDIM * FCK * 2);
  bf16*  rfb = (bf16*)take((size_t)NROI * FCK * 2);
  float* fcx = (float*)take((size_t)NROI * CDIM * 4);
  float* psum = (float*)take(SZ_P);
  float* psq  = (float*)take(SZ_P);
  float* stat = (float*)take(8 * 256 * 4);
  float* scsh = (float*)take(8 * 256 * 4);
  if (off > ws_size) return;  // workspace too small: fail loudly

  // fc split-K slabs reuse Ux (dead after k_pool): 8*512*256*4B = 4MB << 42.5MB
  float* fcp = Ux;

  hipMemsetAsync(xp0, 0, SZ_XP * 2, stream);            // xp0 + xp1 are contiguous
  hipMemsetAsync(stat, 0, 8 * 256 * 4, stream);

  k_wconv3<<<dim3(2304, 3), 256, 0, stream>>>(convw[0], convw[1], convw[2], wball);
  k_cast<<<dim3(4096), 256, 0, stream>>>(fcw, fwb, CDIM * FCK);
  k_convert<<<dim3(HH, NIMG), 256, 0, stream>>>(feat, xp0);

  for (int l = 0; l < 3; ++l) {
    bf16* xin = (l == 1) ? xp1 : xp0;           // conv1<-xp0, conv2<-xp1, conv3<-xp0
    bf16* wbl = wball + (size_t)l * 9 * CDIM * CDIM;
    k_conv<<<dim3(11, 2, NIMG), 256, 0, stream>>>(xin, wbl, y, psum, psq);
    float* su = stat + l * 512; float* sq = su + 256;
    k_partred<<<dim3(16), 256, 0, stream>>>(psum, psq, su, sq);
    float* sc = scsh + l * 512; float* sh = sc + 256;
    k_finalize<<<dim3(1), 256, 0, stream>>>(su, sq, bng[l], bnb[l], sc, sh, 1.f / 41472.f);
    if (l < 2) {
      bf16* xo = (l == 0) ? xp1 : xp0;
      k_normalize<<<dim3(NPX / 8, NIMG), 256, 0, stream>>>(y, sc, sh, xo);
    }
  }
  float* sc3 = scsh + 2 * 512; float* sh3 = sc3 + 256;
  k_p1<<<dim3(HH, NIMG), 256, 0, stream>>>(y, sc3, sh3, Ux);
  k_p2<<<dim3(WW, NIMG), 256, 0, stream>>>(y, sc3, sh3, Ux, Uy, Tt);
  k_pool<<<dim3(NROI), 256, 0, stream>>>(y, sc3, sh3, Ux, Uy, Tt, props, rfb);
  k_fcgemm<<<dim3(8, 4, 8), 256, 0, stream>>>(rfb, fwb, fcp);
  k_fcred<<<dim3(NROI), 256, 0, stream>>>(fcp, fcx);
  float* fsu = stat + 3 * 512; float* fsq = fsu + 256;
  k_stats<<<dim3(8), 256, 0, stream>>>(fcx, fsu, fsq, 64);
  float* fsc = scsh + 3 * 512; float* fsh = fsc + 256;
  k_finalize<<<dim3(1), 256, 0, stream>>>(fsu, fsq, fcg, fcbb, fsc, fsh, 1.f / 512.f);
  k_iou<<<dim3(NROI), 256, 0, stream>>>(fcx, fsc, fsh, iw, ib, out);
}

// Round 6
// 528.329 us; speedup vs baseline: 1.2097x; 1.2097x over previous
//
#include <hip/hip_runtime.h>
#include <hip/hip_bf16.h>
#include <stdint.h>

#define CDIM 256
#define HH 36
#define WW 36
#define NPX 1296          // 36*36
#define PW 38             // padded width (1-px halo)
#define PPIX 1444         // 38*38
#define NIMG 32
#define NROI 512
#define FCK 4096
#define EPS_BN 1e-5f
#define SBLK 192          // stats blocks (41472 rows / 192 = 216 rows/block)

typedef __bf16 bf16;
typedef __bf16 bf16x8 __attribute__((ext_vector_type(8)));
typedef float f32x4 __attribute__((ext_vector_type(4)));
typedef unsigned short us8 __attribute__((ext_vector_type(8)));

// async global->LDS, 16B per lane; LDS dest is wave-uniform base + lane*16
#define GLD16(g, l) __builtin_amdgcn_global_load_lds( \
    (__attribute__((address_space(1))) void*)(g),     \
    (__attribute__((address_space(3))) void*)(l), 16, 0, 0)

// ---------------- weight reorder (all 3 layers): w[co][ci][3][3] f32 -> wb[l][tap][co][ci] bf16
__global__ void k_wconv3(const float* __restrict__ w0, const float* __restrict__ w1,
                         const float* __restrict__ w2, bf16* __restrict__ wb) {
  int l = blockIdx.y;
  const float* ws = (l == 0) ? w0 : (l == 1) ? w1 : w2;
  bf16* dst = wb + (size_t)l * 9 * CDIM * CDIM;
  int i = blockIdx.x * 256 + threadIdx.x;
  if (i >= 9 * CDIM * CDIM) return;
  int tap = i / (CDIM * CDIM);
  int rem = i - tap * (CDIM * CDIM);
  int co = rem >> 8, ci = rem & 255;
  dst[i] = (bf16)ws[(size_t)(co * CDIM + ci) * 9 + tap];
}

// ---------------- generic f32 -> bf16 cast
__global__ void k_cast(const float* __restrict__ src, bf16* __restrict__ dst, int nElem) {
  int i = blockIdx.x * 256 + threadIdx.x;
  if (i < nElem) dst[i] = (bf16)src[i];
}

// ---------------- feat NCHW f32 -> padded NHWC bf16 via LDS transpose
__global__ void k_convert(const float* __restrict__ feat, bf16* __restrict__ xp) {
  __shared__ bf16 tile[CDIM * 38];
  int h = blockIdx.x, n = blockIdx.y, t = threadIdx.x;
  const float* src = feat + (size_t)n * CDIM * NPX + (size_t)h * WW;
#pragma unroll 4
  for (int i = 0; i < 36; ++i) {
    int f = i * 256 + t;
    int c = (int)(((unsigned)f * 7282u) >> 18);  // f/36
    int w = f - c * 36;
    tile[c * 38 + w] = (bf16)src[(size_t)c * NPX + w];
  }
  __syncthreads();
  bf16* dst = xp + (size_t)n * PPIX * CDIM + ((h + 1) * PW + 1) * CDIM + t;
#pragma unroll 4
  for (int w = 0; w < 36; ++w) dst[w * CDIM] = tile[t * 38 + w];
}

// ---------------- conv3x3 implicit GEMM, 128co x 128px tile, bf16 MFMA
// Pure GEMM epilogue (stats de-fused): bf16 NHWC out only.
__global__ __launch_bounds__(256) void k_conv(
    const bf16* __restrict__ xp, const bf16* __restrict__ wb,
    bf16* __restrict__ y)
{
  __shared__ __align__(16) bf16 ldsA[2][4096];
  __shared__ __align__(16) bf16 ldsB[2][4096];
  const int tid = threadIdx.x;
  const int wave = tid >> 6, lane = tid & 63;
  const int pxt = blockIdx.x, cot = blockIdx.y, n = blockIdx.z;

  // staging addressing (XOR chunk swizzle pre-applied to global source)
  const int q = lane >> 2;
  const int gsw = (lane & 3) ^ ((q >> 1) & 3);
  const int rA = wave * 32 + q;
  const bf16* aS0 = wb + (size_t)(cot * 128 + rA) * CDIM + gsw * 8;
  const bf16* aS1 = aS0 + 16 * CDIM;
  int pxa = pxt * 128 + rA;       if (pxa > NPX - 1) pxa = NPX - 1;
  int pxb = pxt * 128 + rA + 16;  if (pxb > NPX - 1) pxb = NPX - 1;
  const int ha = pxa / 36, wa = pxa - ha * 36;
  const int hb = pxb / 36, wbv = pxb - hb * 36;
  const bf16* bS0 = xp + (size_t)n * (PPIX * CDIM) + ((ha + 1) * PW + (wa + 1)) * CDIM + gsw * 8;
  const bf16* bS1 = xp + (size_t)n * (PPIX * CDIM) + ((hb + 1) * PW + (wbv + 1)) * CDIM + gsw * 8;

  // fragment-read addressing
  const int fr = lane & 15, fg = lane >> 4;
  const int fsw = (fg ^ ((fr >> 1) & 3)) * 8;
  const int wco = wave >> 1, wpx = wave & 1;
  const int aoff = (wco * 64 + fr) * 32 + fsw;
  const int boff = (wpx * 64 + fr) * 32 + fsw;

  f32x4 acc[4][4];
#pragma unroll
  for (int i = 0; i < 4; ++i)
#pragma unroll
    for (int j = 0; j < 4; ++j) acc[i][j] = f32x4{0.f, 0.f, 0.f, 0.f};

  { // prologue: stage k=0 (tap 0: dh=-1,dw=-1, ci0=0)
    const int xoff = -(PW + 1) * CDIM;
    GLD16(aS0, &ldsA[0][wave * 1024]);
    GLD16(aS1, &ldsA[0][wave * 1024 + 512]);
    GLD16(bS0 + xoff, &ldsB[0][wave * 1024]);
    GLD16(bS1 + xoff, &ldsB[0][wave * 1024 + 512]);
  }

#pragma unroll 2
  for (int k = 0; k < 72; ++k) {
    const int buf = k & 1;
    __syncthreads();
    if (k + 1 < 72) {
      const int kn = k + 1;
      const int tap = kn >> 3, ci0 = (kn & 7) << 5;
      const int dh = tap / 3 - 1, dw = tap - (tap / 3) * 3 - 1;
      const int woff = tap * (CDIM * CDIM) + ci0;
      const int xoff = (dh * PW + dw) * CDIM + ci0;
      const int nb = buf ^ 1;
      GLD16(aS0 + woff, &ldsA[nb][wave * 1024]);
      GLD16(aS1 + woff, &ldsA[nb][wave * 1024 + 512]);
      GLD16(bS0 + xoff, &ldsB[nb][wave * 1024]);
      GLD16(bS1 + xoff, &ldsB[nb][wave * 1024 + 512]);
    }
    bf16x8 av[4], bv[4];
#pragma unroll
    for (int i = 0; i < 4; ++i) av[i] = *(const bf16x8*)&ldsA[buf][aoff + i * 512];
#pragma unroll
    for (int j = 0; j < 4; ++j) bv[j] = *(const bf16x8*)&ldsB[buf][boff + j * 512];
#pragma unroll
    for (int i = 0; i < 4; ++i)
#pragma unroll
      for (int j = 0; j < 4; ++j)
        acc[i][j] = __builtin_amdgcn_mfma_f32_16x16x32_bf16(av[i], bv[j], acc[i][j], 0, 0, 0);
  }

  // epilogue: C/D layout col(px)=lane&15, row(co)=(lane>>4)*4+reg
#pragma unroll
  for (int j = 0; j < 4; ++j) {
    const int px = pxt * 128 + wpx * 64 + j * 16 + fr;
    if (px < NPX) {
      bf16* dst = y + ((size_t)n * NPX + px) * CDIM + cot * 128 + wco * 64 + fg * 4;
#pragma unroll
      for (int i = 0; i < 4; ++i) {
        f32x4 a = acc[i][j];
        union { bf16 b4[4]; ushort4 u4; } pk;
        pk.b4[0] = (bf16)a[0]; pk.b4[1] = (bf16)a[1];
        pk.b4[2] = (bf16)a[2]; pk.b4[3] = (bf16)a[3];
        *(ushort4*)(dst + i * 16) = pk.u4;
      }
    }
  }
}

// ---------------- per-channel sum/sumsq over bf16 y [41472][256]: 192 partial slots
__global__ void k_statsb(const bf16* __restrict__ y, float* __restrict__ psum,
                         float* __restrict__ psq) {
  __shared__ float lsum[8][256];
  __shared__ float lsq[8][256];
  int t = threadIdx.x;
  int c8 = (t & 31) * 8, rg = t >> 5;           // 32 channel-chunks x 8 row-groups
  size_t row0 = (size_t)blockIdx.x * 216 + rg;
  float s[8], qq[8];
#pragma unroll
  for (int k = 0; k < 8; ++k) { s[k] = 0.f; qq[k] = 0.f; }
  for (int i = 0; i < 27; ++i) {
    const bf16* p = y + (row0 + (size_t)i * 8) * CDIM + c8;
    union { bf16 b8[8]; us8 u; } v;
    v.u = *(const us8*)p;
#pragma unroll
    for (int k = 0; k < 8; ++k) {
      float f = (float)v.b8[k];
      s[k] += f; qq[k] += f * f;
    }
  }
#pragma unroll
  for (int k = 0; k < 8; ++k) { lsum[rg][c8 + k] = s[k]; lsq[rg][c8 + k] = qq[k]; }
  __syncthreads();
  float ss = 0.f, sq2 = 0.f;
#pragma unroll
  for (int g = 0; g < 8; ++g) { ss += lsum[g][t]; sq2 += lsq[g][t]; }
  psum[blockIdx.x * 256 + t] = ss;
  psq[blockIdx.x * 256 + t] = sq2;
}

// ---------------- sum the 192 partial slots (single block, no atomics)
__global__ void k_sred(const float* __restrict__ psum, const float* __restrict__ psq,
                       float* __restrict__ su, float* __restrict__ sq) {
  int c = threadIdx.x;
  float s = 0.f, q = 0.f;
  for (int i = 0; i < SBLK; ++i) { s += psum[i * 256 + c]; q += psq[i * 256 + c]; }
  su[c] = s; sq[c] = q;
}

// ---------------- per-channel sum/sumsq over rows of a [rows][256] f32 array (fc only)
__global__ void k_stats(const float* __restrict__ x, float* __restrict__ sum,
                        float* __restrict__ ssq, int rpb) {
  int c = threadIdx.x;
  size_t base = (size_t)blockIdx.x * rpb;
  float s = 0.f, s2 = 0.f;
  for (int i = 0; i < rpb; ++i) {
    float v = x[(base + i) * CDIM + c];
    s += v; s2 += v * v;
  }
  atomicAdd(&sum[c], s);
  atomicAdd(&ssq[c], s2);
}

__global__ void k_finalize(const float* __restrict__ sum, const float* __restrict__ ssq,
                           const float* __restrict__ g, const float* __restrict__ b,
                           float* __restrict__ sc, float* __restrict__ sh, float invn) {
  int c = threadIdx.x;
  float m = sum[c] * invn;
  float v = ssq[c] * invn - m * m;
  float s = g[c] * rsqrtf(v + EPS_BN);
  sc[c] = s;
  sh[c] = b[c] - m * s;
}

// ---------------- y bf16 NHWC -> BN+ReLU -> padded NHWC bf16 (interior only)
__global__ void k_normalize(const bf16* __restrict__ y, const float* __restrict__ sc,
                            const float* __restrict__ sh, bf16* __restrict__ xp) {
  int t = threadIdx.x;
  int n = blockIdx.y;
  int px = blockIdx.x * 8 + (t >> 5);
  int c8 = (t & 31) * 8;
  const bf16* srcp = y + ((size_t)n * NPX + px) * CDIM + c8;
  union { bf16 b8[8]; us8 u; } in, outp;
  in.u = *(const us8*)srcp;
  int h = px / 36, w = px - h * 36;
#pragma unroll
  for (int i = 0; i < 8; ++i) {
    float v = (float)in.b8[i];
    outp.b8[i] = (bf16)fmaxf(v * sc[c8 + i] + sh[c8 + i], 0.f);
  }
  *(us8*)(xp + (size_t)n * PPIX * CDIM + ((h + 1) * PW + (w + 1)) * CDIM + c8) = outp.u;
}

// ---------------- trapezoid cumsum along W (Ux), inline BN+ReLU of y
__global__ void k_p1(const bf16* __restrict__ y, const float* __restrict__ sc,
                     const float* __restrict__ sh, float* __restrict__ Ux) {
  int c = threadIdx.x, h = blockIdx.x, n = blockIdx.y;
  const bf16* row = y + ((size_t)n * NPX + h * WW) * CDIM + c;
  float* orow = Ux + ((size_t)n * NPX + h * WW) * CDIM + c;
  float s = sc[c], t = sh[c];
  float prev = fmaxf((float)row[0] * s + t, 0.f);
  float run = 0.f;
  orow[0] = 0.f;
  for (int w = 1; w < WW; ++w) {
    float cur = fmaxf((float)row[w * CDIM] * s + t, 0.f);
    run += 0.5f * (prev + cur);
    orow[w * CDIM] = run;
    prev = cur;
  }
}

// ---------------- trapezoid cumsum along H: Uy (of x3) and T (of Ux)
__global__ void k_p2(const bf16* __restrict__ y, const float* __restrict__ sc,
                     const float* __restrict__ sh, const float* __restrict__ Ux,
                     float* __restrict__ Uy, float* __restrict__ T) {
  int c = threadIdx.x, w = blockIdx.x, n = blockIdx.y;
  size_t base = (size_t)n * NPX * CDIM + (size_t)w * CDIM + c;
  float s = sc[c], t = sh[c];
  float prevF = fmaxf((float)y[base] * s + t, 0.f);
  float prevU = Ux[base];
  float runF = 0.f, runU = 0.f;
  Uy[base] = 0.f; T[base] = 0.f;
  for (int h = 1; h < HH; ++h) {
    size_t idx = base + (size_t)h * WW * CDIM;
    float f = fmaxf((float)y[idx] * s + t, 0.f);
    float u = Ux[idx];
    runF += 0.5f * (prevF + f);
    runU += 0.5f * (prevU + u);
    Uy[idx] = runF; T[idx] = runU;
    prevF = f; prevU = u;
  }
}

// ---------------- PrRoI pool: block=(roi, ch-half), 128 threads; rf[roi][c*16+i*4+j] bf16
__global__ __launch_bounds__(128) void k_pool(
    const bf16* __restrict__ y, const float* __restrict__ sc,
    const float* __restrict__ sh, const float* __restrict__ Ux,
    const float* __restrict__ Uy, const float* __restrict__ T,
    const float* __restrict__ props, bf16* __restrict__ rf) {
  int roi = blockIdx.x;
  int c = blockIdx.y * 128 + threadIdx.x;
  int b = roi >> 4;
  const float* pr = props + (size_t)roi * 4;
  float x1 = pr[0] * 20.f, yy1 = pr[1] * 20.f;
  float x2 = (pr[0] + pr[2]) * 20.f, yy2 = (pr[1] + pr[3]) * 20.f;
  float bw = (x2 - x1) * 0.25f, bh = (yy2 - yy1) * 0.25f;
  float px0a[5], px1a[5], py0a[5], py1a[5];
  int wx[5], hy[5];
#pragma unroll
  for (int j = 0; j < 5; ++j) {
    float xs = fminf(fmaxf(x1 + bw * j, 0.f), 35.f);
    int wi = (int)floorf(xs); wi = wi < 0 ? 0 : (wi > 34 ? 34 : wi);
    float sx = xs - (float)wi;
    float p1 = 0.5f * sx * sx;
    wx[j] = wi; px1a[j] = p1; px0a[j] = sx - p1;
    float ys = fminf(fmaxf(yy1 + bh * j, 0.f), 35.f);
    int hi = (int)floorf(ys); hi = hi < 0 ? 0 : (hi > 34 ? 34 : hi);
    float sy = ys - (float)hi;
    float q1 = 0.5f * sy * sy;
    hy[j] = hi; py1a[j] = q1; py0a[j] = sy - q1;
  }
  float s = sc[c], tt = sh[c];
  const float* yb  = (const float*)nullptr;
  const size_t nb = (size_t)b * NPX * CDIM + c;
  const bf16* ybb = y + nb;
  const float* Uxb = Ux + nb;
  const float* Uyb = Uy + nb;
  const float* Tb  = T + nb;
  (void)yb;
  float G[5][5];
#pragma unroll
  for (int i = 0; i < 5; ++i) {
    int h0 = hy[i];
    int rb0 = h0 * (WW * CDIM), rb1 = rb0 + WW * CDIM;
#pragma unroll
    for (int j = 0; j < 5; ++j) {
      int w0 = wx[j];
      int i00 = rb0 + w0 * CDIM;
      int i01 = i00 + CDIM;
      int i10 = rb1 + w0 * CDIM;
      int i11 = i10 + CDIM;
      float f00 = fmaxf((float)ybb[i00] * s + tt, 0.f);
      float f01 = fmaxf((float)ybb[i01] * s + tt, 0.f);
      float f10 = fmaxf((float)ybb[i10] * s + tt, 0.f);
      float f11 = fmaxf((float)ybb[i11] * s + tt, 0.f);
      G[i][j] = Tb[i00] + Uyb[i00] * px0a[j] + Uyb[i01] * px1a[j]
              + py0a[i] * (Uxb[i00] + f00 * px0a[j] + f01 * px1a[j])
              + py1a[i] * (Uxb[i10] + f10 * px0a[j] + f11 * px1a[j]);
    }
  }
  float area = bw * bh;
  float inv = area > 1e-8f ? 1.f / area : 0.f;
  bf16 outv[16];
#pragma unroll
  for (int i = 0; i < 4; ++i)
#pragma unroll
    for (int j = 0; j < 4; ++j) {
      float d = G[i + 1][j + 1] - G[i][j + 1] - G[i + 1][j] + G[i][j];
      outv[i * 4 + j] = (bf16)(d * inv);
    }
  bf16* dst = rf + (size_t)roi * FCK + c * 16;
  *(us8*)(dst)     = *(us8*)&outv[0];
  *(us8*)(dst + 8) = *(us8*)&outv[8];
}

// ---------------- fc GEMM: fcp[ks][roi][o] = partial, split-K=8, MFMA, no atomics
__global__ __launch_bounds__(256) void k_fcgemm(const bf16* __restrict__ rf,
                                                const bf16* __restrict__ fw,
                                                float* __restrict__ fcp) {
  int tid = threadIdx.x, wave = tid >> 6, lane = tid & 63;
  int wo = wave >> 1, wr = wave & 1;
  int rt = blockIdx.x, ot = blockIdx.y, ks = blockIdx.z;
  int fr = lane & 15, fg = lane >> 4;
  const bf16* ap = fw + (size_t)(ot * 64 + wo * 32 + fr) * FCK + ks * 512 + fg * 8;
  const bf16* bp = rf + (size_t)(rt * 64 + wr * 32 + fr) * FCK + ks * 512 + fg * 8;
  f32x4 acc[2][2];
#pragma unroll
  for (int i = 0; i < 2; ++i)
#pragma unroll
    for (int j = 0; j < 2; ++j) acc[i][j] = f32x4{0.f, 0.f, 0.f, 0.f};
#pragma unroll 4
  for (int k = 0; k < 512; k += 32) {
    bf16x8 a0 = *(const bf16x8*)(ap + k);
    bf16x8 a1 = *(const bf16x8*)(ap + 16 * FCK + k);
    bf16x8 b0 = *(const bf16x8*)(bp + k);
    bf16x8 b1 = *(const bf16x8*)(bp + 16 * FCK + k);
    acc[0][0] = __builtin_amdgcn_mfma_f32_16x16x32_bf16(a0, b0, acc[0][0], 0, 0, 0);
    acc[0][1] = __builtin_amdgcn_mfma_f32_16x16x32_bf16(a0, b1, acc[0][1], 0, 0, 0);
    acc[1][0] = __builtin_amdgcn_mfma_f32_16x16x32_bf16(a1, b0, acc[1][0], 0, 0, 0);
    acc[1][1] = __builtin_amdgcn_mfma_f32_16x16x32_bf16(a1, b1, acc[1][1], 0, 0, 0);
  }
#pragma unroll
  for (int i = 0; i < 2; ++i)
#pragma unroll
    for (int j = 0; j < 2; ++j) {
      int o = ot * 64 + wo * 32 + i * 16 + fg * 4;
      int r = rt * 64 + wr * 32 + j * 16 + fr;
      *(f32x4*)(fcp + ((size_t)ks * NROI + r) * CDIM + o) = acc[i][j];
    }
}

// ---------------- reduce split-K slabs: fcx[r][o] = sum_ks fcp[ks][r][o]
__global__ void k_fcred(const float* __restrict__ fcp, float* __restrict__ fcx) {
  int r = blockIdx.x, o = threadIdx.x;
  float s = 0.f;
#pragma unroll
  for (int ks = 0; ks < 8; ++ks) s += fcp[((size_t)ks * NROI + r) * CDIM + o];
  fcx[(size_t)r * CDIM + o] = s;
}

// ---------------- fc BN + ReLU + iou head
__global__ void k_iou(const float* __restrict__ fcx, const float* __restrict__ sc,
                      const float* __restrict__ sh, const float* __restrict__ iw,
                      const float* __restrict__ ib, float* __restrict__ out) {
  __shared__ float red[4];
  int roi = blockIdx.x, t = threadIdx.x;
  float v = fcx[(size_t)roi * CDIM + t];
  v = fmaxf(v * sc[t] + sh[t], 0.f) * iw[t];
#pragma unroll
  for (int o = 32; o > 0; o >>= 1) v += __shfl_down(v, o);
  if ((t & 63) == 0) red[t >> 6] = v;
  __syncthreads();
  if (t == 0) out[roi] = red[0] + red[1] + red[2] + red[3] + ib[0];
}

extern "C" void kernel_launch(void* const* d_in, const int* in_sizes, int n_in,
                              void* d_out, int out_size, void* d_ws, size_t ws_size,
                              hipStream_t stream) {
  (void)in_sizes; (void)n_in; (void)out_size;
  const float* feat  = (const float*)d_in[0];
  const float* props = (const float*)d_in[1];
  const float* convw[3] = {(const float*)d_in[2], (const float*)d_in[6], (const float*)d_in[10]};
  const float* bng[3]   = {(const float*)d_in[4], (const float*)d_in[8], (const float*)d_in[12]};
  const float* bnb[3]   = {(const float*)d_in[5], (const float*)d_in[9], (const float*)d_in[13]};
  const float* fcw  = (const float*)d_in[14];
  const float* fcg  = (const float*)d_in[16];
  const float* fcbb = (const float*)d_in[17];
  const float* iw   = (const float*)d_in[18];
  const float* ib   = (const float*)d_in[19];
  float* out = (float*)d_out;

  char* w = (char*)d_ws;
  size_t off = 0;
  auto take = [&](size_t sz) -> char* { char* p = w + off; off += (sz + 255) & ~(size_t)255; return p; };
  const size_t SZ_XP = (size_t)NIMG * PPIX * CDIM * 2;
  const size_t SZ_YB = (size_t)NIMG * NPX * CDIM * 2;   // bf16 y
  const size_t SZ_U  = (size_t)NIMG * NPX * CDIM * 4;   // f32 integrals
  const size_t SZ_P  = (size_t)SBLK * 256 * 4;          // partial stats (one array)
  bf16*  xp0 = (bf16*)take(SZ_XP);
  bf16*  xp1 = (bf16*)take(SZ_XP);
  bf16*  y   = (bf16*)take(SZ_YB);
  float* Ux  = (float*)take(SZ_U);
  float* Uy  = (float*)take(SZ_U);
  float* Tt  = (float*)take(SZ_U);
  bf16*  wball = (bf16*)take((size_t)3 * 9 * CDIM * CDIM * 2);
  bf16*  fwb = (bf16*)take((size_t)CDIM * FCK * 2);
  bf16*  rfb = (bf16*)take((size_t)NROI * FCK * 2);
  float* fcx = (float*)take((size_t)NROI * CDIM * 4);
  float* psum = (float*)take(SZ_P);
  float* psq  = (float*)take(SZ_P);
  float* stat = (float*)take(8 * 256 * 4);
  float* scsh = (float*)take(8 * 256 * 4);
  if (off > ws_size) return;  // workspace too small: fail loudly

  // fc split-K slabs reuse Ux (dead after k_pool): 8*512*256*4B = 4MB << 42.5MB
  float* fcp = Ux;

  hipMemsetAsync(xp0, 0, SZ_XP * 2, stream);            // xp0 + xp1 are contiguous
  hipMemsetAsync(stat, 0, 8 * 256 * 4, stream);         // fc k_stats atomics

  k_wconv3<<<dim3(2304, 3), 256, 0, stream>>>(convw[0], convw[1], convw[2], wball);
  k_cast<<<dim3(4096), 256, 0, stream>>>(fcw, fwb, CDIM * FCK);
  k_convert<<<dim3(HH, NIMG), 256, 0, stream>>>(feat, xp0);

  for (int l = 0; l < 3; ++l) {
    bf16* xin = (l == 1) ? xp1 : xp0;           // conv1<-xp0, conv2<-xp1, conv3<-xp0
    bf16* wbl = wball + (size_t)l * 9 * CDIM * CDIM;
    k_conv<<<dim3(11, 2, NIMG), 256, 0, stream>>>(xin, wbl, y);
    float* su = stat + l * 512; float* sq = su + 256;
    k_statsb<<<dim3(SBLK), 256, 0, stream>>>(y, psum, psq);
    k_sred<<<dim3(1), 256, 0, stream>>>(psum, psq, su, sq);
    float* sc = scsh + l * 512; float* sh = sc + 256;
    k_finalize<<<dim3(1), 256, 0, stream>>>(su, sq, bng[l], bnb[l], sc, sh, 1.f / 41472.f);
    if (l < 2) {
      bf16* xo = (l == 0) ? xp1 : xp0;
      k_normalize<<<dim3(NPX / 8, NIMG), 256, 0, stream>>>(y, sc, sh, xo);
    }
  }
  float* sc3 = scsh + 2 * 512; float* sh3 = sc3 + 256;
  k_p1<<<dim3(HH, NIMG), 256, 0, stream>>>(y, sc3, sh3, Ux);
  k_p2<<<dim3(WW, NIMG), 256, 0, stream>>>(y, sc3, sh3, Ux, Uy, Tt);
  k_pool<<<dim3(NROI, 2), 128, 0, stream>>>(y, sc3, sh3, Ux, Uy, Tt, props, rfb);
  k_fcgemm<<<dim3(8, 4, 8), 256, 0, stream>>>(rfb, fwb, fcp);
  k_fcred<<<dim3(NROI), 256, 0, stream>>>(fcp, fcx);
  float* fsu = stat + 3 * 512; float* fsq = fsu + 256;
  k_stats<<<dim3(8), 256, 0, stream>>>(fcx, fsu, fsq, 64);
  float* fsc = scsh + 3 * 512; float* fsh = fsc + 256;
  k_finalize<<<dim3(1), 256, 0, stream>>>(fsu, fsq, fcg, fcbb, fsc, fsh, 1.f / 512.f);
  k_iou<<<dim3(NROI), 256, 0, stream>>>(fcx, fsc, fsh, iw, ib, out);
}

// Round 7
// 490.235 us; speedup vs baseline: 1.3037x; 1.0777x over previous
//
#include <hip/hip_runtime.h>
#include <hip/hip_bf16.h>
#include <stdint.h>

#define CDIM 256
#define HH 36
#define WW 36
#define NPX 1296          // 36*36
#define PW 38             // padded width (1-px halo)
#define PPIX 1444         // 38*38
#define NIMG 32
#define NROI 512
#define FCK 4096
#define EPS_BN 1e-5f
#define SBLK 192          // stats blocks (41472 rows / 192 = 216 rows/block)

typedef __bf16 bf16;
typedef __bf16 bf16x8 __attribute__((ext_vector_type(8)));
typedef float f32x4 __attribute__((ext_vector_type(4)));
typedef unsigned short us8 __attribute__((ext_vector_type(8)));

// async global->LDS, 16B per lane; LDS dest is wave-uniform base + lane*16
#define GLD16(g, l) __builtin_amdgcn_global_load_lds( \
    (__attribute__((address_space(1))) void*)(g),     \
    (__attribute__((address_space(3))) void*)(l), 16, 0, 0)

// ---------------- weight reorder (all 3 layers): w[co][ci][3][3] f32 -> wb[l][tap][co][ci] bf16
__global__ void k_wconv3(const float* __restrict__ w0, const float* __restrict__ w1,
                         const float* __restrict__ w2, bf16* __restrict__ wb) {
  int l = blockIdx.y;
  const float* ws = (l == 0) ? w0 : (l == 1) ? w1 : w2;
  bf16* dst = wb + (size_t)l * 9 * CDIM * CDIM;
  int i = blockIdx.x * 256 + threadIdx.x;
  if (i >= 9 * CDIM * CDIM) return;
  int tap = i / (CDIM * CDIM);
  int rem = i - tap * (CDIM * CDIM);
  int co = rem >> 8, ci = rem & 255;
  dst[i] = (bf16)ws[(size_t)(co * CDIM + ci) * 9 + tap];
}

// ---------------- generic f32 -> bf16 cast
__global__ void k_cast(const float* __restrict__ src, bf16* __restrict__ dst, int nElem) {
  int i = blockIdx.x * 256 + threadIdx.x;
  if (i < nElem) dst[i] = (bf16)src[i];
}

// ---------------- feat NCHW f32 -> padded NHWC bf16 via LDS transpose
__global__ void k_convert(const float* __restrict__ feat, bf16* __restrict__ xp) {
  __shared__ bf16 tile[CDIM * 38];
  int h = blockIdx.x, n = blockIdx.y, t = threadIdx.x;
  const float* src = feat + (size_t)n * CDIM * NPX + (size_t)h * WW;
#pragma unroll 4
  for (int i = 0; i < 36; ++i) {
    int f = i * 256 + t;
    int c = (int)(((unsigned)f * 7282u) >> 18);  // f/36
    int w = f - c * 36;
    tile[c * 38 + w] = (bf16)src[(size_t)c * NPX + w];
  }
  __syncthreads();
  bf16* dst = xp + (size_t)n * PPIX * CDIM + ((h + 1) * PW + 1) * CDIM + t;
#pragma unroll 4
  for (int w = 0; w < 36; ++w) dst[w * CDIM] = tile[t * 38 + w];
}

// ---------------- conv3x3 implicit GEMM, 128co x 128px tile, bf16 MFMA
__global__ __launch_bounds__(256) void k_conv(
    const bf16* __restrict__ xp, const bf16* __restrict__ wb,
    bf16* __restrict__ y)
{
  __shared__ __align__(16) bf16 ldsA[2][4096];
  __shared__ __align__(16) bf16 ldsB[2][4096];
  const int tid = threadIdx.x;
  const int wave = tid >> 6, lane = tid & 63;
  const int pxt = blockIdx.x, cot = blockIdx.y, n = blockIdx.z;

  // staging addressing (XOR chunk swizzle pre-applied to global source)
  const int q = lane >> 2;
  const int gsw = (lane & 3) ^ ((q >> 1) & 3);
  const int rA = wave * 32 + q;
  const bf16* aS0 = wb + (size_t)(cot * 128 + rA) * CDIM + gsw * 8;
  const bf16* aS1 = aS0 + 16 * CDIM;
  int pxa = pxt * 128 + rA;       if (pxa > NPX - 1) pxa = NPX - 1;
  int pxb = pxt * 128 + rA + 16;  if (pxb > NPX - 1) pxb = NPX - 1;
  const int ha = pxa / 36, wa = pxa - ha * 36;
  const int hb = pxb / 36, wbv = pxb - hb * 36;
  const bf16* bS0 = xp + (size_t)n * (PPIX * CDIM) + ((ha + 1) * PW + (wa + 1)) * CDIM + gsw * 8;
  const bf16* bS1 = xp + (size_t)n * (PPIX * CDIM) + ((hb + 1) * PW + (wbv + 1)) * CDIM + gsw * 8;

  // fragment-read addressing
  const int fr = lane & 15, fg = lane >> 4;
  const int fsw = (fg ^ ((fr >> 1) & 3)) * 8;
  const int wco = wave >> 1, wpx = wave & 1;
  const int aoff = (wco * 64 + fr) * 32 + fsw;
  const int boff = (wpx * 64 + fr) * 32 + fsw;

  f32x4 acc[4][4];
#pragma unroll
  for (int i = 0; i < 4; ++i)
#pragma unroll
    for (int j = 0; j < 4; ++j) acc[i][j] = f32x4{0.f, 0.f, 0.f, 0.f};

  { // prologue: stage k=0 (tap 0: dh=-1,dw=-1, ci0=0)
    const int xoff = -(PW + 1) * CDIM;
    GLD16(aS0, &ldsA[0][wave * 1024]);
    GLD16(aS1, &ldsA[0][wave * 1024 + 512]);
    GLD16(bS0 + xoff, &ldsB[0][wave * 1024]);
    GLD16(bS1 + xoff, &ldsB[0][wave * 1024 + 512]);
  }

#pragma unroll 2
  for (int k = 0; k < 72; ++k) {
    const int buf = k & 1;
    __syncthreads();
    if (k + 1 < 72) {
      const int kn = k + 1;
      const int tap = kn >> 3, ci0 = (kn & 7) << 5;
      const int dh = tap / 3 - 1, dw = tap - (tap / 3) * 3 - 1;
      const int woff = tap * (CDIM * CDIM) + ci0;
      const int xoff = (dh * PW + dw) * CDIM + ci0;
      const int nb = buf ^ 1;
      GLD16(aS0 + woff, &ldsA[nb][wave * 1024]);
      GLD16(aS1 + woff, &ldsA[nb][wave * 1024 + 512]);
      GLD16(bS0 + xoff, &ldsB[nb][wave * 1024]);
      GLD16(bS1 + xoff, &ldsB[nb][wave * 1024 + 512]);
    }
    bf16x8 av[4], bv[4];
#pragma unroll
    for (int i = 0; i < 4; ++i) av[i] = *(const bf16x8*)&ldsA[buf][aoff + i * 512];
#pragma unroll
    for (int j = 0; j < 4; ++j) bv[j] = *(const bf16x8*)&ldsB[buf][boff + j * 512];
#pragma unroll
    for (int i = 0; i < 4; ++i)
#pragma unroll
      for (int j = 0; j < 4; ++j)
        acc[i][j] = __builtin_amdgcn_mfma_f32_16x16x32_bf16(av[i], bv[j], acc[i][j], 0, 0, 0);
  }

  // epilogue: C/D layout col(px)=lane&15, row(co)=(lane>>4)*4+reg
#pragma unroll
  for (int j = 0; j < 4; ++j) {
    const int px = pxt * 128 + wpx * 64 + j * 16 + fr;
    if (px < NPX) {
      bf16* dst = y + ((size_t)n * NPX + px) * CDIM + cot * 128 + wco * 64 + fg * 4;
#pragma unroll
      for (int i = 0; i < 4; ++i) {
        f32x4 a = acc[i][j];
        union { bf16 b4[4]; ushort4 u4; } pk;
        pk.b4[0] = (bf16)a[0]; pk.b4[1] = (bf16)a[1];
        pk.b4[2] = (bf16)a[2]; pk.b4[3] = (bf16)a[3];
        *(ushort4*)(dst + i * 16) = pk.u4;
      }
    }
  }
}

// ---------------- per-channel sum/sumsq over bf16 y [41472][256]: 192 partial slots
__global__ void k_statsb(const bf16* __restrict__ y, float* __restrict__ psum,
                         float* __restrict__ psq) {
  __shared__ float lsum[8][256];
  __shared__ float lsq[8][256];
  int t = threadIdx.x;
  int c8 = (t & 31) * 8, rg = t >> 5;           // 32 channel-chunks x 8 row-groups
  size_t row0 = (size_t)blockIdx.x * 216 + rg;
  float s[8], qq[8];
#pragma unroll
  for (int k = 0; k < 8; ++k) { s[k] = 0.f; qq[k] = 0.f; }
  for (int i = 0; i < 27; ++i) {
    const bf16* p = y + (row0 + (size_t)i * 8) * CDIM + c8;
    union { bf16 b8[8]; us8 u; } v;
    v.u = *(const us8*)p;
#pragma unroll
    for (int k = 0; k < 8; ++k) {
      float f = (float)v.b8[k];
      s[k] += f; qq[k] += f * f;
    }
  }
#pragma unroll
  for (int k = 0; k < 8; ++k) { lsum[rg][c8 + k] = s[k]; lsq[rg][c8 + k] = qq[k]; }
  __syncthreads();
  float ss = 0.f, sq2 = 0.f;
#pragma unroll
  for (int g = 0; g < 8; ++g) { ss += lsum[g][t]; sq2 += lsq[g][t]; }
  psum[blockIdx.x * 256 + t] = ss;
  psq[blockIdx.x * 256 + t] = sq2;
}

// ---------------- sum the 192 partial slots (single block, no atomics)
__global__ void k_sred(const float* __restrict__ psum, const float* __restrict__ psq,
                       float* __restrict__ su, float* __restrict__ sq) {
  int c = threadIdx.x;
  float s = 0.f, q = 0.f;
  for (int i = 0; i < SBLK; ++i) { s += psum[i * 256 + c]; q += psq[i * 256 + c]; }
  su[c] = s; sq[c] = q;
}

// ---------------- per-channel sum/sumsq over rows of a [rows][256] f32 array (fc only)
__global__ void k_stats(const float* __restrict__ x, float* __restrict__ sum,
                        float* __restrict__ ssq, int rpb) {
  int c = threadIdx.x;
  size_t base = (size_t)blockIdx.x * rpb;
  float s = 0.f, s2 = 0.f;
  for (int i = 0; i < rpb; ++i) {
    float v = x[(base + i) * CDIM + c];
    s += v; s2 += v * v;
  }
  atomicAdd(&sum[c], s);
  atomicAdd(&ssq[c], s2);
}

__global__ void k_finalize(const float* __restrict__ sum, const float* __restrict__ ssq,
                           const float* __restrict__ g, const float* __restrict__ b,
                           float* __restrict__ sc, float* __restrict__ sh, float invn) {
  int c = threadIdx.x;
  float m = sum[c] * invn;
  float v = ssq[c] * invn - m * m;
  float s = g[c] * rsqrtf(v + EPS_BN);
  sc[c] = s;
  sh[c] = b[c] - m * s;
}

// ---------------- y bf16 NHWC -> BN+ReLU -> padded NHWC bf16 (interior only)
__global__ void k_normalize(const bf16* __restrict__ y, const float* __restrict__ sc,
                            const float* __restrict__ sh, bf16* __restrict__ xp) {
  int t = threadIdx.x;
  int n = blockIdx.y;
  int px = blockIdx.x * 8 + (t >> 5);
  int c8 = (t & 31) * 8;
  const bf16* srcp = y + ((size_t)n * NPX + px) * CDIM + c8;
  union { bf16 b8[8]; us8 u; } in, outp;
  in.u = *(const us8*)srcp;
  int h = px / 36, w = px - h * 36;
#pragma unroll
  for (int i = 0; i < 8; ++i) {
    float v = (float)in.b8[i];
    outp.b8[i] = (bf16)fmaxf(v * sc[c8 + i] + sh[c8 + i], 0.f);
  }
  *(us8*)(xp + (size_t)n * PPIX * CDIM + ((h + 1) * PW + (w + 1)) * CDIM + c8) = outp.u;
}

// ---------------- hat-function cumulative integral: H(u) = int_{-inf}^{u} max(0,1-|x|) dx
__device__ __forceinline__ float hatH(float u) {
  u = fminf(fmaxf(u, -1.f), 1.f);
  float p = u + 1.f;
  return (u < 0.f) ? 0.5f * p * p : 0.5f + u * (1.f - 0.5f * u);
}

// ---------------- PrRoI pool, direct separable form (no integral images)
// out[i][j] = (sum_h wy_i[h] * sum_w wx_j[w] * relu(bn(y[h,w]))) / area
// exact-equal to the reference integral-image formulation.
__global__ __launch_bounds__(128) void k_pool(
    const bf16* __restrict__ y, const float* __restrict__ sc,
    const float* __restrict__ sh, const float* __restrict__ props,
    bf16* __restrict__ rf) {
  int roi = blockIdx.x;
  int c = blockIdx.y * 128 + threadIdx.x;
  int b = roi >> 4;
  const float* pr = props + (size_t)roi * 4;
  float x1 = pr[0] * 20.f, yy1 = pr[1] * 20.f;
  float x2 = (pr[0] + pr[2]) * 20.f, yy2 = (pr[1] + pr[3]) * 20.f;
  float bw = (x2 - x1) * 0.25f, bh = (yy2 - yy1) * 0.25f;

  float xs[5], ys[5];
#pragma unroll
  for (int j = 0; j < 5; ++j) {
    xs[j] = fminf(fmaxf(x1 + bw * j, 0.f), 35.f);
    ys[j] = fminf(fmaxf(yy1 + bh * j, 0.f), 35.f);
  }
  // per-cell hat-integral weights over <=5 nodes starting at floor(a)
  float wxv[4][5], wyv[4][5];
  int sx[4], sy[4];
#pragma unroll
  for (int j = 0; j < 4; ++j) {
    float a = xs[j], bb = xs[j + 1];
    int s = (int)floorf(a);
    sx[j] = s;
#pragma unroll
    for (int k = 0; k < 5; ++k) {
      float w = (float)(s + k);
      wxv[j][k] = hatH(bb - w) - hatH(a - w);
    }
    float ay = ys[j], by = ys[j + 1];
    int t = (int)floorf(ay);
    sy[j] = t;
#pragma unroll
    for (int k = 0; k < 5; ++k) {
      float w = (float)(t + k);
      wyv[j][k] = hatH(by - w) - hatH(ay - w);
    }
  }

  float s_ = sc[c], t_ = sh[c];
  const bf16* yb = y + (size_t)b * NPX * CDIM + c;
  float acc[4][4];
#pragma unroll
  for (int i = 0; i < 4; ++i)
#pragma unroll
    for (int j = 0; j < 4; ++j) acc[i][j] = 0.f;

#pragma unroll
  for (int i = 0; i < 4; ++i) {
#pragma unroll
    for (int ky = 0; ky < 5; ++ky) {
      float wy = wyv[i][ky];
      if (wy == 0.f) continue;            // block-uniform branch
      int h = sy[i] + ky; if (h > 35) h = 35;
      const bf16* rowp = yb + h * (WW * CDIM);
#pragma unroll
      for (int j = 0; j < 4; ++j) {
        float rd = 0.f;
#pragma unroll
        for (int kx = 0; kx < 5; ++kx) {
          int w = sx[j] + kx; if (w > 35) w = 35;
          float f = fmaxf((float)rowp[w * CDIM] * s_ + t_, 0.f);
          rd += wxv[j][kx] * f;
        }
        acc[i][j] += wy * rd;
      }
    }
  }

  float area = bw * bh;
  float inv = area > 1e-8f ? 1.f / area : 0.f;
  bf16 outv[16];
#pragma unroll
  for (int i = 0; i < 4; ++i)
#pragma unroll
    for (int j = 0; j < 4; ++j)
      outv[i * 4 + j] = (bf16)(acc[i][j] * inv);
  bf16* dst = rf + (size_t)roi * FCK + c * 16;
  *(us8*)(dst)     = *(us8*)&outv[0];
  *(us8*)(dst + 8) = *(us8*)&outv[8];
}

// ---------------- fc GEMM: fcp[ks][roi][o] = partial, split-K=8, MFMA, no atomics
__global__ __launch_bounds__(256) void k_fcgemm(const bf16* __restrict__ rf,
                                                const bf16* __restrict__ fw,
                                                float* __restrict__ fcp) {
  int tid = threadIdx.x, wave = tid >> 6, lane = tid & 63;
  int wo = wave >> 1, wr = wave & 1;
  int rt = blockIdx.x, ot = blockIdx.y, ks = blockIdx.z;
  int fr = lane & 15, fg = lane >> 4;
  const bf16* ap = fw + (size_t)(ot * 64 + wo * 32 + fr) * FCK + ks * 512 + fg * 8;
  const bf16* bp = rf + (size_t)(rt * 64 + wr * 32 + fr) * FCK + ks * 512 + fg * 8;
  f32x4 acc[2][2];
#pragma unroll
  for (int i = 0; i < 2; ++i)
#pragma unroll
    for (int j = 0; j < 2; ++j) acc[i][j] = f32x4{0.f, 0.f, 0.f, 0.f};
#pragma unroll 4
  for (int k = 0; k < 512; k += 32) {
    bf16x8 a0 = *(const bf16x8*)(ap + k);
    bf16x8 a1 = *(const bf16x8*)(ap + 16 * FCK + k);
    bf16x8 b0 = *(const bf16x8*)(bp + k);
    bf16x8 b1 = *(const bf16x8*)(bp + 16 * FCK + k);
    acc[0][0] = __builtin_amdgcn_mfma_f32_16x16x32_bf16(a0, b0, acc[0][0], 0, 0, 0);
    acc[0][1] = __builtin_amdgcn_mfma_f32_16x16x32_bf16(a0, b1, acc[0][1], 0, 0, 0);
    acc[1][0] = __builtin_amdgcn_mfma_f32_16x16x32_bf16(a1, b0, acc[1][0], 0, 0, 0);
    acc[1][1] = __builtin_amdgcn_mfma_f32_16x16x32_bf16(a1, b1, acc[1][1], 0, 0, 0);
  }
#pragma unroll
  for (int i = 0; i < 2; ++i)
#pragma unroll
    for (int j = 0; j < 2; ++j) {
      int o = ot * 64 + wo * 32 + i * 16 + fg * 4;
      int r = rt * 64 + wr * 32 + j * 16 + fr;
      *(f32x4*)(fcp + ((size_t)ks * NROI + r) * CDIM + o) = acc[i][j];
    }
}

// ---------------- reduce split-K slabs: fcx[r][o] = sum_ks fcp[ks][r][o]
__global__ void k_fcred(const float* __restrict__ fcp, float* __restrict__ fcx) {
  int r = blockIdx.x, o = threadIdx.x;
  float s = 0.f;
#pragma unroll
  for (int ks = 0; ks < 8; ++ks) s += fcp[((size_t)ks * NROI + r) * CDIM + o];
  fcx[(size_t)r * CDIM + o] = s;
}

// ---------------- fc BN + ReLU + iou head
__global__ void k_iou(const float* __restrict__ fcx, const float* __restrict__ sc,
                      const float* __restrict__ sh, const float* __restrict__ iw,
                      const float* __restrict__ ib, float* __restrict__ out) {
  __shared__ float red[4];
  int roi = blockIdx.x, t = threadIdx.x;
  float v = fcx[(size_t)roi * CDIM + t];
  v = fmaxf(v * sc[t] + sh[t], 0.f) * iw[t];
#pragma unroll
  for (int o = 32; o > 0; o >>= 1) v += __shfl_down(v, o);
  if ((t & 63) == 0) red[t >> 6] = v;
  __syncthreads();
  if (t == 0) out[roi] = red[0] + red[1] + red[2] + red[3] + ib[0];
}

extern "C" void kernel_launch(void* const* d_in, const int* in_sizes, int n_in,
                              void* d_out, int out_size, void* d_ws, size_t ws_size,
                              hipStream_t stream) {
  (void)in_sizes; (void)n_in; (void)out_size;
  const float* feat  = (const float*)d_in[0];
  const float* props = (const float*)d_in[1];
  const float* convw[3] = {(const float*)d_in[2], (const float*)d_in[6], (const float*)d_in[10]};
  const float* bng[3]   = {(const float*)d_in[4], (const float*)d_in[8], (const float*)d_in[12]};
  const float* bnb[3]   = {(const float*)d_in[5], (const float*)d_in[9], (const float*)d_in[13]};
  const float* fcw  = (const float*)d_in[14];
  const float* fcg  = (const float*)d_in[16];
  const float* fcbb = (const float*)d_in[17];
  const float* iw   = (const float*)d_in[18];
  const float* ib   = (const float*)d_in[19];
  float* out = (float*)d_out;

  char* w = (char*)d_ws;
  size_t off = 0;
  auto take = [&](size_t sz) -> char* { char* p = w + off; off += (sz + 255) & ~(size_t)255; return p; };
  const size_t SZ_XP = (size_t)NIMG * PPIX * CDIM * 2;
  const size_t SZ_YB = (size_t)NIMG * NPX * CDIM * 2;   // bf16 y
  const size_t SZ_P  = (size_t)SBLK * 256 * 4;          // partial stats (one array)
  bf16*  xp0 = (bf16*)take(SZ_XP);
  bf16*  xp1 = (bf16*)take(SZ_XP);
  bf16*  y   = (bf16*)take(SZ_YB);
  bf16*  wball = (bf16*)take((size_t)3 * 9 * CDIM * CDIM * 2);
  bf16*  fwb = (bf16*)take((size_t)CDIM * FCK * 2);
  bf16*  rfb = (bf16*)take((size_t)NROI * FCK * 2);
  float* fcx = (float*)take((size_t)NROI * CDIM * 4);
  float* fcp = (float*)take((size_t)8 * NROI * CDIM * 4);
  float* psum = (float*)take(SZ_P);
  float* psq  = (float*)take(SZ_P);
  float* stat = (float*)take(8 * 256 * 4);
  float* scsh = (float*)take(8 * 256 * 4);
  if (off > ws_size) return;  // workspace too small: fail loudly

  hipMemsetAsync(xp0, 0, SZ_XP * 2, stream);            // xp0 + xp1 are contiguous
  hipMemsetAsync(stat, 0, 8 * 256 * 4, stream);         // fc k_stats atomics

  k_wconv3<<<dim3(2304, 3), 256, 0, stream>>>(convw[0], convw[1], convw[2], wball);
  k_cast<<<dim3(4096), 256, 0, stream>>>(fcw, fwb, CDIM * FCK);
  k_convert<<<dim3(HH, NIMG), 256, 0, stream>>>(feat, xp0);

  for (int l = 0; l < 3; ++l) {
    bf16* xin = (l == 1) ? xp1 : xp0;           // conv1<-xp0, conv2<-xp1, conv3<-xp0
    bf16* wbl = wball + (size_t)l * 9 * CDIM * CDIM;
    k_conv<<<dim3(11, 2, NIMG), 256, 0, stream>>>(xin, wbl, y);
    float* su = stat + l * 512; float* sq = su + 256;
    k_statsb<<<dim3(SBLK), 256, 0, stream>>>(y, psum, psq);
    k_sred<<<dim3(1), 256, 0, stream>>>(psum, psq, su, sq);
    float* sc = scsh + l * 512; float* sh = sc + 256;
    k_finalize<<<dim3(1), 256, 0, stream>>>(su, sq, bng[l], bnb[l], sc, sh, 1.f / 41472.f);
    if (l < 2) {
      bf16* xo = (l == 0) ? xp1 : xp0;
      k_normalize<<<dim3(NPX / 8, NIMG), 256, 0, stream>>>(y, sc, sh, xo);
    }
  }
  float* sc3 = scsh + 2 * 512; float* sh3 = sc3 + 256;
  k_pool<<<dim3(NROI, 2), 128, 0, stream>>>(y, sc3, sh3, props, rfb);
  k_fcgemm<<<dim3(8, 4, 8), 256, 0, stream>>>(rfb, fwb, fcp);
  k_fcred<<<dim3(NROI), 256, 0, stream>>>(fcp, fcx);
  float* fsu = stat + 3 * 512; float* fsq = fsu + 256;
  k_stats<<<dim3(8), 256, 0, stream>>>(fcx, fsu, fsq, 64);
  float* fsc = scsh + 3 * 512; float* fsh = fsc + 256;
  k_finalize<<<dim3(1), 256, 0, stream>>>(fsu, fsq, fcg, fcbb, fsc, fsh, 1.f / 512.f);
  k_iou<<<dim3(NROI), 256, 0, stream>>>(fcx, fsc, fsh, iw, ib, out);
}

// Round 8
// 487.970 us; speedup vs baseline: 1.3097x; 1.0046x over previous
//
#include <hip/hip_runtime.h>
#include <hip/hip_bf16.h>
#include <stdint.h>

#define CDIM 256
#define HH 36
#define WW 36
#define NPX 1296          // 36*36
#define PW 38             // padded width (1-px halo)
#define PPIX 1444         // 38*38
#define NIMG 32
#define NROI 512
#define FCK 4096
#define EPS_BN 1e-5f
#define SBLK 192          // stats blocks (41472 rows / 192 = 216 rows/block)
#define GPXT 324          // flattened px tiles: 41472/128

typedef __bf16 bf16;
typedef __bf16 bf16x8 __attribute__((ext_vector_type(8)));
typedef float f32x4 __attribute__((ext_vector_type(4)));
typedef unsigned short us8 __attribute__((ext_vector_type(8)));

// async global->LDS, 16B per lane; LDS dest is wave-uniform base + lane*16
#define GLD16(g, l) __builtin_amdgcn_global_load_lds( \
    (__attribute__((address_space(1))) void*)(g),     \
    (__attribute__((address_space(3))) void*)(l), 16, 0, 0)

// ---------------- weight reorder (all 3 layers): w[co][ci][3][3] f32 -> wb[l][tap][co][ci] bf16
__global__ void k_wconv3(const float* __restrict__ w0, const float* __restrict__ w1,
                         const float* __restrict__ w2, bf16* __restrict__ wb) {
  int l = blockIdx.y;
  const float* ws = (l == 0) ? w0 : (l == 1) ? w1 : w2;
  bf16* dst = wb + (size_t)l * 9 * CDIM * CDIM;
  int i = blockIdx.x * 256 + threadIdx.x;
  if (i >= 9 * CDIM * CDIM) return;
  int tap = i / (CDIM * CDIM);
  int rem = i - tap * (CDIM * CDIM);
  int co = rem >> 8, ci = rem & 255;
  dst[i] = (bf16)ws[(size_t)(co * CDIM + ci) * 9 + tap];
}

// ---------------- generic f32 -> bf16 cast
__global__ void k_cast(const float* __restrict__ src, bf16* __restrict__ dst, int nElem) {
  int i = blockIdx.x * 256 + threadIdx.x;
  if (i < nElem) dst[i] = (bf16)src[i];
}

// ---------------- feat NCHW f32 -> padded NHWC bf16 via LDS transpose
__global__ void k_convert(const float* __restrict__ feat, bf16* __restrict__ xp) {
  __shared__ bf16 tile[CDIM * 38];
  int h = blockIdx.x, n = blockIdx.y, t = threadIdx.x;
  const float* src = feat + (size_t)n * CDIM * NPX + (size_t)h * WW;
#pragma unroll 4
  for (int i = 0; i < 36; ++i) {
    int f = i * 256 + t;
    int c = (int)(((unsigned)f * 7282u) >> 18);  // f/36
    int w = f - c * 36;
    tile[c * 38 + w] = (bf16)src[(size_t)c * NPX + w];
  }
  __syncthreads();
  bf16* dst = xp + (size_t)n * PPIX * CDIM + ((h + 1) * PW + 1) * CDIM + t;
#pragma unroll 4
  for (int w = 0; w < 36; ++w) dst[w * CDIM] = tile[t * 38 + w];
}

// ---------------- conv3x3 implicit GEMM, 128co x 128px tile, bf16 MFMA
// px flattened across images (41472 = 324 tiles x 128, guard-free);
// XCD-swizzled: xcd = B&7 owns 81 contiguous (cot,gpxt) tiles.
__global__ __launch_bounds__(256) void k_conv(
    const bf16* __restrict__ xp, const bf16* __restrict__ wb,
    bf16* __restrict__ y)
{
  __shared__ __align__(16) bf16 ldsA[2][4096];
  __shared__ __align__(16) bf16 ldsB[2][4096];
  const int tid = threadIdx.x;
  const int wave = tid >> 6, lane = tid & 63;

  // XCD swizzle (dispatcher is B%8 round-robin; proven by r2 FETCH collapse)
  const int B = blockIdx.x;
  const int g = (B & 7) * 81 + (B >> 3);        // 0..647 tile id, contiguous per XCD
  const int cot = g / GPXT, gpxt = g - cot * GPXT;

  // staging addressing (XOR chunk swizzle pre-applied to global source)
  const int q = lane >> 2;
  const int gsw = (lane & 3) ^ ((q >> 1) & 3);
  const int rA = wave * 32 + q;
  const bf16* aS0 = wb + (size_t)(cot * 128 + rA) * CDIM + gsw * 8;
  const bf16* aS1 = aS0 + 16 * CDIM;
  const int gpx0 = gpxt * 128 + rA;             // < 41472 always
  const int gpx1 = gpx0 + 16;
  const int n0 = (int)(((unsigned)gpx0 * 51782u) >> 26);   // /1296
  const int n1 = (int)(((unsigned)gpx1 * 51782u) >> 26);
  const int p0 = gpx0 - n0 * 1296, p1 = gpx1 - n1 * 1296;
  const int h0 = (int)(((unsigned)p0 * 7282u) >> 18);      // /36
  const int h1 = (int)(((unsigned)p1 * 7282u) >> 18);
  const int w0 = p0 - h0 * 36, w1 = p1 - h1 * 36;
  const bf16* bS0 = xp + (size_t)n0 * (PPIX * CDIM) + ((h0 + 1) * PW + (w0 + 1)) * CDIM + gsw * 8;
  const bf16* bS1 = xp + (size_t)n1 * (PPIX * CDIM) + ((h1 + 1) * PW + (w1 + 1)) * CDIM + gsw * 8;

  // fragment-read addressing
  const int fr = lane & 15, fg = lane >> 4;
  const int fsw = (fg ^ ((fr >> 1) & 3)) * 8;
  const int wco = wave >> 1, wpx = wave & 1;
  const int aoff = (wco * 64 + fr) * 32 + fsw;
  const int boff = (wpx * 64 + fr) * 32 + fsw;

  f32x4 acc[4][4];
#pragma unroll
  for (int i = 0; i < 4; ++i)
#pragma unroll
    for (int j = 0; j < 4; ++j) acc[i][j] = f32x4{0.f, 0.f, 0.f, 0.f};

  { // prologue: stage k=0 (tap 0: dh=-1,dw=-1, ci0=0)
    const int xoff = -(PW + 1) * CDIM;
    GLD16(aS0, &ldsA[0][wave * 1024]);
    GLD16(aS1, &ldsA[0][wave * 1024 + 512]);
    GLD16(bS0 + xoff, &ldsB[0][wave * 1024]);
    GLD16(bS1 + xoff, &ldsB[0][wave * 1024 + 512]);
  }

#pragma unroll 2
  for (int k = 0; k < 72; ++k) {
    const int buf = k & 1;
    __syncthreads();
    if (k + 1 < 72) {
      const int kn = k + 1;
      const int tap = kn >> 3, ci0 = (kn & 7) << 5;
      const int dh = tap / 3 - 1, dw = tap - (tap / 3) * 3 - 1;
      const int woff = tap * (CDIM * CDIM) + ci0;
      const int xoff = (dh * PW + dw) * CDIM + ci0;
      const int nb = buf ^ 1;
      GLD16(aS0 + woff, &ldsA[nb][wave * 1024]);
      GLD16(aS1 + woff, &ldsA[nb][wave * 1024 + 512]);
      GLD16(bS0 + xoff, &ldsB[nb][wave * 1024]);
      GLD16(bS1 + xoff, &ldsB[nb][wave * 1024 + 512]);
    }
    bf16x8 av[4], bv[4];
#pragma unroll
    for (int i = 0; i < 4; ++i) av[i] = *(const bf16x8*)&ldsA[buf][aoff + i * 512];
#pragma unroll
    for (int j = 0; j < 4; ++j) bv[j] = *(const bf16x8*)&ldsB[buf][boff + j * 512];
#pragma unroll
    for (int i = 0; i < 4; ++i)
#pragma unroll
      for (int j = 0; j < 4; ++j)
        acc[i][j] = __builtin_amdgcn_mfma_f32_16x16x32_bf16(av[i], bv[j], acc[i][j], 0, 0, 0);
  }

  // epilogue: C/D layout col(px)=lane&15, row(co)=(lane>>4)*4+reg; guard-free
#pragma unroll
  for (int j = 0; j < 4; ++j) {
    const int gpx = gpxt * 128 + wpx * 64 + j * 16 + fr;
    bf16* dst = y + (size_t)gpx * CDIM + cot * 128 + wco * 64 + fg * 4;
#pragma unroll
    for (int i = 0; i < 4; ++i) {
      f32x4 a = acc[i][j];
      union { bf16 b4[4]; ushort4 u4; } pk;
      pk.b4[0] = (bf16)a[0]; pk.b4[1] = (bf16)a[1];
      pk.b4[2] = (bf16)a[2]; pk.b4[3] = (bf16)a[3];
      *(ushort4*)(dst + i * 16) = pk.u4;
    }
  }
}

// ---------------- per-channel sum/sumsq over bf16 y [41472][256]: 192 partial slots
__global__ void k_statsb(const bf16* __restrict__ y, float* __restrict__ psum,
                         float* __restrict__ psq) {
  __shared__ float lsum[8][256];
  __shared__ float lsq[8][256];
  int t = threadIdx.x;
  int c8 = (t & 31) * 8, rg = t >> 5;           // 32 channel-chunks x 8 row-groups
  size_t row0 = (size_t)blockIdx.x * 216 + rg;
  float s[8], qq[8];
#pragma unroll
  for (int k = 0; k < 8; ++k) { s[k] = 0.f; qq[k] = 0.f; }
  for (int i = 0; i < 27; ++i) {
    const bf16* p = y + (row0 + (size_t)i * 8) * CDIM + c8;
    union { bf16 b8[8]; us8 u; } v;
    v.u = *(const us8*)p;
#pragma unroll
    for (int k = 0; k < 8; ++k) {
      float f = (float)v.b8[k];
      s[k] += f; qq[k] += f * f;
    }
  }
#pragma unroll
  for (int k = 0; k < 8; ++k) { lsum[rg][c8 + k] = s[k]; lsq[rg][c8 + k] = qq[k]; }
  __syncthreads();
  float ss = 0.f, sq2 = 0.f;
#pragma unroll
  for (int g = 0; g < 8; ++g) { ss += lsum[g][t]; sq2 += lsq[g][t]; }
  psum[blockIdx.x * 256 + t] = ss;
  psq[blockIdx.x * 256 + t] = sq2;
}

// ---------------- sum partial slots + finalize BN coefficients (one block)
__global__ void k_sredfin(const float* __restrict__ psum, const float* __restrict__ psq,
                          const float* __restrict__ g, const float* __restrict__ b,
                          float* __restrict__ sc, float* __restrict__ sh, float invn) {
  int c = threadIdx.x;
  float s = 0.f, q = 0.f;
  for (int i = 0; i < SBLK; ++i) { s += psum[i * 256 + c]; q += psq[i * 256 + c]; }
  float m = s * invn;
  float v = q * invn - m * m;
  float sca = g[c] * rsqrtf(v + EPS_BN);
  sc[c] = sca;
  sh[c] = b[c] - m * sca;
}

// ---------------- per-channel sum/sumsq over rows of a [rows][256] f32 array (fc only)
__global__ void k_stats(const float* __restrict__ x, float* __restrict__ sum,
                        float* __restrict__ ssq, int rpb) {
  int c = threadIdx.x;
  size_t base = (size_t)blockIdx.x * rpb;
  float s = 0.f, s2 = 0.f;
  for (int i = 0; i < rpb; ++i) {
    float v = x[(base + i) * CDIM + c];
    s += v; s2 += v * v;
  }
  atomicAdd(&sum[c], s);
  atomicAdd(&ssq[c], s2);
}

__global__ void k_finalize(const float* __restrict__ sum, const float* __restrict__ ssq,
                           const float* __restrict__ g, const float* __restrict__ b,
                           float* __restrict__ sc, float* __restrict__ sh, float invn) {
  int c = threadIdx.x;
  float m = sum[c] * invn;
  float v = ssq[c] * invn - m * m;
  float s = g[c] * rsqrtf(v + EPS_BN);
  sc[c] = s;
  sh[c] = b[c] - m * s;
}

// ---------------- y bf16 NHWC -> BN+ReLU -> padded NHWC bf16 (interior only)
__global__ void k_normalize(const bf16* __restrict__ y, const float* __restrict__ sc,
                            const float* __restrict__ sh, bf16* __restrict__ xp) {
  int t = threadIdx.x;
  int n = blockIdx.y;
  int px = blockIdx.x * 8 + (t >> 5);
  int c8 = (t & 31) * 8;
  const bf16* srcp = y + ((size_t)n * NPX + px) * CDIM + c8;
  union { bf16 b8[8]; us8 u; } in, outp;
  in.u = *(const us8*)srcp;
  int h = px / 36, w = px - h * 36;
#pragma unroll
  for (int i = 0; i < 8; ++i) {
    float v = (float)in.b8[i];
    outp.b8[i] = (bf16)fmaxf(v * sc[c8 + i] + sh[c8 + i], 0.f);
  }
  *(us8*)(xp + (size_t)n * PPIX * CDIM + ((h + 1) * PW + (w + 1)) * CDIM + c8) = outp.u;
}

// ---------------- hat-function cumulative integral: H(u) = int_{-inf}^{u} max(0,1-|x|) dx
__device__ __forceinline__ float hatH(float u) {
  u = fminf(fmaxf(u, -1.f), 1.f);
  float p = u + 1.f;
  return (u < 0.f) ? 0.5f * p * p : 0.5f + u * (1.f - 0.5f * u);
}

// ---------------- PrRoI pool, direct separable form (no integral images)
__global__ __launch_bounds__(128) void k_pool(
    const bf16* __restrict__ y, const float* __restrict__ sc,
    const float* __restrict__ sh, const float* __restrict__ props,
    bf16* __restrict__ rf) {
  int roi = blockIdx.x;
  int c = blockIdx.y * 128 + threadIdx.x;
  int b = roi >> 4;
  const float* pr = props + (size_t)roi * 4;
  float x1 = pr[0] * 20.f, yy1 = pr[1] * 20.f;
  float x2 = (pr[0] + pr[2]) * 20.f, yy2 = (pr[1] + pr[3]) * 20.f;
  float bw = (x2 - x1) * 0.25f, bh = (yy2 - yy1) * 0.25f;

  float xs[5], ys[5];
#pragma unroll
  for (int j = 0; j < 5; ++j) {
    xs[j] = fminf(fmaxf(x1 + bw * j, 0.f), 35.f);
    ys[j] = fminf(fmaxf(yy1 + bh * j, 0.f), 35.f);
  }
  float wxv[4][5], wyv[4][5];
  int sx[4], sy[4];
#pragma unroll
  for (int j = 0; j < 4; ++j) {
    float a = xs[j], bb = xs[j + 1];
    int s = (int)floorf(a);
    sx[j] = s;
#pragma unroll
    for (int k = 0; k < 5; ++k) {
      float w = (float)(s + k);
      wxv[j][k] = hatH(bb - w) - hatH(a - w);
    }
    float ay = ys[j], by = ys[j + 1];
    int t = (int)floorf(ay);
    sy[j] = t;
#pragma unroll
    for (int k = 0; k < 5; ++k) {
      float w = (float)(t + k);
      wyv[j][k] = hatH(by - w) - hatH(ay - w);
    }
  }

  float s_ = sc[c], t_ = sh[c];
  const bf16* yb = y + (size_t)b * NPX * CDIM + c;
  float acc[4][4];
#pragma unroll
  for (int i = 0; i < 4; ++i)
#pragma unroll
    for (int j = 0; j < 4; ++j) acc[i][j] = 0.f;

#pragma unroll
  for (int i = 0; i < 4; ++i) {
#pragma unroll
    for (int ky = 0; ky < 5; ++ky) {
      float wy = wyv[i][ky];
      if (wy == 0.f) continue;            // block-uniform branch
      int h = sy[i] + ky; if (h > 35) h = 35;
      const bf16* rowp = yb + h * (WW * CDIM);
#pragma unroll
      for (int j = 0; j < 4; ++j) {
        float rd = 0.f;
#pragma unroll
        for (int kx = 0; kx < 5; ++kx) {
          int w = sx[j] + kx; if (w > 35) w = 35;
          float f = fmaxf((float)rowp[w * CDIM] * s_ + t_, 0.f);
          rd += wxv[j][kx] * f;
        }
        acc[i][j] += wy * rd;
      }
    }
  }

  float area = bw * bh;
  float inv = area > 1e-8f ? 1.f / area : 0.f;
  bf16 outv[16];
#pragma unroll
  for (int i = 0; i < 4; ++i)
#pragma unroll
    for (int j = 0; j < 4; ++j)
      outv[i * 4 + j] = (bf16)(acc[i][j] * inv);
  bf16* dst = rf + (size_t)roi * FCK + c * 16;
  *(us8*)(dst)     = *(us8*)&outv[0];
  *(us8*)(dst + 8) = *(us8*)&outv[8];
}

// ---------------- fc GEMM: fcp[ks][roi][o] = partial, split-K=8, MFMA, no atomics
__global__ __launch_bounds__(256) void k_fcgemm(const bf16* __restrict__ rf,
                                                const bf16* __restrict__ fw,
                                                float* __restrict__ fcp) {
  int tid = threadIdx.x, wave = tid >> 6, lane = tid & 63;
  int wo = wave >> 1, wr = wave & 1;
  int rt = blockIdx.x, ot = blockIdx.y, ks = blockIdx.z;
  int fr = lane & 15, fg = lane >> 4;
  const bf16* ap = fw + (size_t)(ot * 64 + wo * 32 + fr) * FCK + ks * 512 + fg * 8;
  const bf16* bp = rf + (size_t)(rt * 64 + wr * 32 + fr) * FCK + ks * 512 + fg * 8;
  f32x4 acc[2][2];
#pragma unroll
  for (int i = 0; i < 2; ++i)
#pragma unroll
    for (int j = 0; j < 2; ++j) acc[i][j] = f32x4{0.f, 0.f, 0.f, 0.f};
#pragma unroll 4
  for (int k = 0; k < 512; k += 32) {
    bf16x8 a0 = *(const bf16x8*)(ap + k);
    bf16x8 a1 = *(const bf16x8*)(ap + 16 * FCK + k);
    bf16x8 b0 = *(const bf16x8*)(bp + k);
    bf16x8 b1 = *(const bf16x8*)(bp + 16 * FCK + k);
    acc[0][0] = __builtin_amdgcn_mfma_f32_16x16x32_bf16(a0, b0, acc[0][0], 0, 0, 0);
    acc[0][1] = __builtin_amdgcn_mfma_f32_16x16x32_bf16(a0, b1, acc[0][1], 0, 0, 0);
    acc[1][0] = __builtin_amdgcn_mfma_f32_16x16x32_bf16(a1, b0, acc[1][0], 0, 0, 0);
    acc[1][1] = __builtin_amdgcn_mfma_f32_16x16x32_bf16(a1, b1, acc[1][1], 0, 0, 0);
  }
#pragma unroll
  for (int i = 0; i < 2; ++i)
#pragma unroll
    for (int j = 0; j < 2; ++j) {
      int o = ot * 64 + wo * 32 + i * 16 + fg * 4;
      int r = rt * 64 + wr * 32 + j * 16 + fr;
      *(f32x4*)(fcp + ((size_t)ks * NROI + r) * CDIM + o) = acc[i][j];
    }
}

// ---------------- reduce split-K slabs: fcx[r][o] = sum_ks fcp[ks][r][o]
__global__ void k_fcred(const float* __restrict__ fcp, float* __restrict__ fcx) {
  int r = blockIdx.x, o = threadIdx.x;
  float s = 0.f;
#pragma unroll
  for (int ks = 0; ks < 8; ++ks) s += fcp[((size_t)ks * NROI + r) * CDIM + o];
  fcx[(size_t)r * CDIM + o] = s;
}

// ---------------- fc BN + ReLU + iou head
__global__ void k_iou(const float* __restrict__ fcx, const float* __restrict__ sc,
                      const float* __restrict__ sh, const float* __restrict__ iw,
                      const float* __restrict__ ib, float* __restrict__ out) {
  __shared__ float red[4];
  int roi = blockIdx.x, t = threadIdx.x;
  float v = fcx[(size_t)roi * CDIM + t];
  v = fmaxf(v * sc[t] + sh[t], 0.f) * iw[t];
#pragma unroll
  for (int o = 32; o > 0; o >>= 1) v += __shfl_down(v, o);
  if ((t & 63) == 0) red[t >> 6] = v;
  __syncthreads();
  if (t == 0) out[roi] = red[0] + red[1] + red[2] + red[3] + ib[0];
}

extern "C" void kernel_launch(void* const* d_in, const int* in_sizes, int n_in,
                              void* d_out, int out_size, void* d_ws, size_t ws_size,
                              hipStream_t stream) {
  (void)in_sizes; (void)n_in; (void)out_size;
  const float* feat  = (const float*)d_in[0];
  const float* props = (const float*)d_in[1];
  const float* convw[3] = {(const float*)d_in[2], (const float*)d_in[6], (const float*)d_in[10]};
  const float* bng[3]   = {(const float*)d_in[4], (const float*)d_in[8], (const float*)d_in[12]};
  const float* bnb[3]   = {(const float*)d_in[5], (const float*)d_in[9], (const float*)d_in[13]};
  const float* fcw  = (const float*)d_in[14];
  const float* fcg  = (const float*)d_in[16];
  const float* fcbb = (const float*)d_in[17];
  const float* iw   = (const float*)d_in[18];
  const float* ib   = (const float*)d_in[19];
  float* out = (float*)d_out;

  char* w = (char*)d_ws;
  size_t off = 0;
  auto take = [&](size_t sz) -> char* { char* p = w + off; off += (sz + 255) & ~(size_t)255; return p; };
  const size_t SZ_XP = (size_t)NIMG * PPIX * CDIM * 2;
  const size_t SZ_YB = (size_t)NIMG * NPX * CDIM * 2;   // bf16 y
  const size_t SZ_P  = (size_t)SBLK * 256 * 4;          // partial stats (one array)
  bf16*  xp0 = (bf16*)take(SZ_XP);
  bf16*  xp1 = (bf16*)take(SZ_XP);
  bf16*  y   = (bf16*)take(SZ_YB);
  bf16*  wball = (bf16*)take((size_t)3 * 9 * CDIM * CDIM * 2);
  bf16*  fwb = (bf16*)take((size_t)CDIM * FCK * 2);
  bf16*  rfb = (bf16*)take((size_t)NROI * FCK * 2);
  float* fcx = (float*)take((size_t)NROI * CDIM * 4);
  float* fcp = (float*)take((size_t)8 * NROI * CDIM * 4);
  float* psum = (float*)take(SZ_P);
  float* psq  = (float*)take(SZ_P);
  float* stat = (float*)take(8 * 256 * 4);
  float* scsh = (float*)take(8 * 256 * 4);
  if (off > ws_size) return;  // workspace too small: fail loudly

  hipMemsetAsync(xp0, 0, SZ_XP * 2, stream);            // xp0 + xp1 are contiguous
  hipMemsetAsync(stat, 0, 8 * 256 * 4, stream);         // fc k_stats atomics

  k_wconv3<<<dim3(2304, 3), 256, 0, stream>>>(convw[0], convw[1], convw[2], wball);
  k_cast<<<dim3(4096), 256, 0, stream>>>(fcw, fwb, CDIM * FCK);
  k_convert<<<dim3(HH, NIMG), 256, 0, stream>>>(feat, xp0);

  for (int l = 0; l < 3; ++l) {
    bf16* xin = (l == 1) ? xp1 : xp0;           // conv1<-xp0, conv2<-xp1, conv3<-xp0
    bf16* wbl = wball + (size_t)l * 9 * CDIM * CDIM;
    k_conv<<<dim3(648), 256, 0, stream>>>(xin, wbl, y);
    k_statsb<<<dim3(SBLK), 256, 0, stream>>>(y, psum, psq);
    float* sc = scsh + l * 512; float* sh = sc + 256;
    k_sredfin<<<dim3(1), 256, 0, stream>>>(psum, psq, bng[l], bnb[l], sc, sh, 1.f / 41472.f);
    if (l < 2) {
      bf16* xo = (l == 0) ? xp1 : xp0;
      k_normalize<<<dim3(NPX / 8, NIMG), 256, 0, stream>>>(y, sc, sh, xo);
    }
  }
  float* sc3 = scsh + 2 * 512; float* sh3 = sc3 + 256;
  k_pool<<<dim3(NROI, 2), 128, 0, stream>>>(y, sc3, sh3, props, rfb);
  k_fcgemm<<<dim3(8, 4, 8), 256, 0, stream>>>(rfb, fwb, fcp);
  k_fcred<<<dim3(NROI), 256, 0, stream>>>(fcp, fcx);
  float* fsu = stat + 3 * 512; float* fsq = fsu + 256;
  k_stats<<<dim3(8), 256, 0, stream>>>(fcx, fsu, fsq, 64);
  float* fsc = scsh + 3 * 512; float* fsh = fsc + 256;
  k_finalize<<<dim3(1), 256, 0, stream>>>(fsu, fsq, fcg, fcbb, fsc, fsh, 1.f / 512.f);
  k_iou<<<dim3(NROI), 256, 0, stream>>>(fcx, fsc, fsh, iw, ib, out);
}

// Round 9
// 461.957 us; speedup vs baseline: 1.3835x; 1.0563x over previous
//
#include <hip/hip_runtime.h>
#include <hip/hip_bf16.h>
#include <stdint.h>

#define CDIM 256
#define HH 36
#define WW 36
#define NPX 1296          // 36*36
#define PW 38             // padded width (1-px halo)
#define PPIX 1444         // 38*38
#define NIMG 32
#define NROI 512
#define FCK 4096
#define EPS_BN 1e-5f
#define SBLK 192          // stats blocks (41472 rows / 192 = 216 rows/block)
#define NWC (9*CDIM*CDIM) // weights per conv layer

typedef __bf16 bf16;
typedef __bf16 bf16x8 __attribute__((ext_vector_type(8)));
typedef float f32x4 __attribute__((ext_vector_type(4)));
typedef unsigned short us8 __attribute__((ext_vector_type(8)));

// async global->LDS, 16B per lane; LDS dest is wave-uniform base + lane*16
#define GLD16(g, l) __builtin_amdgcn_global_load_lds( \
    (__attribute__((address_space(1))) void*)(g),     \
    (__attribute__((address_space(3))) void*)(l), 16, 0, 0)

// ---------------- merged prep: 3x conv weight reorder + fc weight cast
__global__ void k_prep(const float* __restrict__ w0, const float* __restrict__ w1,
                       const float* __restrict__ w2, const float* __restrict__ fcw,
                       bf16* __restrict__ wb, bf16* __restrict__ fwb) {
  int i = blockIdx.x * 256 + threadIdx.x;
  if (i < 3 * NWC) {
    int l = i / NWC, r = i - l * NWC;
    const float* ws = (l == 0) ? w0 : (l == 1) ? w1 : w2;
    int tap = r / (CDIM * CDIM);
    int rem = r - tap * (CDIM * CDIM);
    int co = rem >> 8, ci = rem & 255;
    wb[i] = (bf16)ws[(size_t)(co * CDIM + ci) * 9 + tap];
  } else {
    int j = i - 3 * NWC;
    if (j < CDIM * FCK) fwb[j] = (bf16)fcw[j];
  }
}

// ---------------- feat NCHW f32 -> padded NHWC bf16 via LDS transpose
__global__ void k_convert(const float* __restrict__ feat, bf16* __restrict__ xp) {
  __shared__ bf16 tile[CDIM * 38];
  int h = blockIdx.x, n = blockIdx.y, t = threadIdx.x;
  const float* src = feat + (size_t)n * CDIM * NPX + (size_t)h * WW;
#pragma unroll 4
  for (int i = 0; i < 36; ++i) {
    int f = i * 256 + t;
    int c = (int)(((unsigned)f * 7282u) >> 18);  // f/36
    int w = f - c * 36;
    tile[c * 38 + w] = (bf16)src[(size_t)c * NPX + w];
  }
  __syncthreads();
  bf16* dst = xp + (size_t)n * PPIX * CDIM + ((h + 1) * PW + 1) * CDIM + t;
#pragma unroll 4
  for (int w = 0; w < 36; ++w) dst[w * CDIM] = tile[t * 38 + w];
}

// ---------------- conv3x3 implicit GEMM, 128co x 128px tile, bf16 MFMA
// r7 body + r2 XCD swizzle: XCD k owns images {k,k+8,k+16,k+24}, both cot halves
// (4.2 MB working set per XCD -> fits 4 MB L2; r8's 8-image variant thrashed).
__global__ __launch_bounds__(256) void k_conv(
    const bf16* __restrict__ xp, const bf16* __restrict__ wb,
    bf16* __restrict__ y)
{
  __shared__ __align__(16) bf16 ldsA[2][4096];
  __shared__ __align__(16) bf16 ldsB[2][4096];
  const int tid = threadIdx.x;
  const int wave = tid >> 6, lane = tid & 63;

  const int B = blockIdx.x;
  const int xcd = B & 7, idx = B >> 3;        // idx 0..87
  const int ng = idx / 22, inner = idx - ng * 22;
  const int n = (ng << 3) + xcd;              // image 0..31
  const int cot = inner / 11, pxt = inner - cot * 11;

  // staging addressing (XOR chunk swizzle pre-applied to global source)
  const int q = lane >> 2;
  const int gsw = (lane & 3) ^ ((q >> 1) & 3);
  const int rA = wave * 32 + q;
  const bf16* aS0 = wb + (size_t)(cot * 128 + rA) * CDIM + gsw * 8;
  const bf16* aS1 = aS0 + 16 * CDIM;
  int pxa = pxt * 128 + rA;       if (pxa > NPX - 1) pxa = NPX - 1;
  int pxb = pxt * 128 + rA + 16;  if (pxb > NPX - 1) pxb = NPX - 1;
  const int ha = pxa / 36, wa = pxa - ha * 36;
  const int hb = pxb / 36, wbv = pxb - hb * 36;
  const bf16* bS0 = xp + (size_t)n * (PPIX * CDIM) + ((ha + 1) * PW + (wa + 1)) * CDIM + gsw * 8;
  const bf16* bS1 = xp + (size_t)n * (PPIX * CDIM) + ((hb + 1) * PW + (wbv + 1)) * CDIM + gsw * 8;

  // fragment-read addressing
  const int fr = lane & 15, fg = lane >> 4;
  const int fsw = (fg ^ ((fr >> 1) & 3)) * 8;
  const int wco = wave >> 1, wpx = wave & 1;
  const int aoff = (wco * 64 + fr) * 32 + fsw;
  const int boff = (wpx * 64 + fr) * 32 + fsw;

  f32x4 acc[4][4];
#pragma unroll
  for (int i = 0; i < 4; ++i)
#pragma unroll
    for (int j = 0; j < 4; ++j) acc[i][j] = f32x4{0.f, 0.f, 0.f, 0.f};

  { // prologue: stage k=0 (tap 0: dh=-1,dw=-1, ci0=0)
    const int xoff = -(PW + 1) * CDIM;
    GLD16(aS0, &ldsA[0][wave * 1024]);
    GLD16(aS1, &ldsA[0][wave * 1024 + 512]);
    GLD16(bS0 + xoff, &ldsB[0][wave * 1024]);
    GLD16(bS1 + xoff, &ldsB[0][wave * 1024 + 512]);
  }

#pragma unroll 2
  for (int k = 0; k < 72; ++k) {
    const int buf = k & 1;
    __syncthreads();
    if (k + 1 < 72) {
      const int kn = k + 1;
      const int tap = kn >> 3, ci0 = (kn & 7) << 5;
      const int dh = tap / 3 - 1, dw = tap - (tap / 3) * 3 - 1;
      const int woff = tap * (CDIM * CDIM) + ci0;
      const int xoff = (dh * PW + dw) * CDIM + ci0;
      const int nb = buf ^ 1;
      GLD16(aS0 + woff, &ldsA[nb][wave * 1024]);
      GLD16(aS1 + woff, &ldsA[nb][wave * 1024 + 512]);
      GLD16(bS0 + xoff, &ldsB[nb][wave * 1024]);
      GLD16(bS1 + xoff, &ldsB[nb][wave * 1024 + 512]);
    }
    bf16x8 av[4], bv[4];
#pragma unroll
    for (int i = 0; i < 4; ++i) av[i] = *(const bf16x8*)&ldsA[buf][aoff + i * 512];
#pragma unroll
    for (int j = 0; j < 4; ++j) bv[j] = *(const bf16x8*)&ldsB[buf][boff + j * 512];
#pragma unroll
    for (int i = 0; i < 4; ++i)
#pragma unroll
      for (int j = 0; j < 4; ++j)
        acc[i][j] = __builtin_amdgcn_mfma_f32_16x16x32_bf16(av[i], bv[j], acc[i][j], 0, 0, 0);
  }

  // epilogue: C/D layout col(px)=lane&15, row(co)=(lane>>4)*4+reg
#pragma unroll
  for (int j = 0; j < 4; ++j) {
    const int px = pxt * 128 + wpx * 64 + j * 16 + fr;
    if (px < NPX) {
      bf16* dst = y + ((size_t)n * NPX + px) * CDIM + cot * 128 + wco * 64 + fg * 4;
#pragma unroll
      for (int i = 0; i < 4; ++i) {
        f32x4 a = acc[i][j];
        union { bf16 b4[4]; ushort4 u4; } pk;
        pk.b4[0] = (bf16)a[0]; pk.b4[1] = (bf16)a[1];
        pk.b4[2] = (bf16)a[2]; pk.b4[3] = (bf16)a[3];
        *(ushort4*)(dst + i * 16) = pk.u4;
      }
    }
  }
}

// ---------------- per-channel sum/sumsq over bf16 y [41472][256]: 192 partial slots
__global__ void k_statsb(const bf16* __restrict__ y, float* __restrict__ psum,
                         float* __restrict__ psq) {
  __shared__ float lsum[8][256];
  __shared__ float lsq[8][256];
  int t = threadIdx.x;
  int c8 = (t & 31) * 8, rg = t >> 5;           // 32 channel-chunks x 8 row-groups
  size_t row0 = (size_t)blockIdx.x * 216 + rg;
  float s[8], qq[8];
#pragma unroll
  for (int k = 0; k < 8; ++k) { s[k] = 0.f; qq[k] = 0.f; }
  for (int i = 0; i < 27; ++i) {
    const bf16* p = y + (row0 + (size_t)i * 8) * CDIM + c8;
    union { bf16 b8[8]; us8 u; } v;
    v.u = *(const us8*)p;
#pragma unroll
    for (int k = 0; k < 8; ++k) {
      float f = (float)v.b8[k];
      s[k] += f; qq[k] += f * f;
    }
  }
#pragma unroll
  for (int k = 0; k < 8; ++k) { lsum[rg][c8 + k] = s[k]; lsq[rg][c8 + k] = qq[k]; }
  __syncthreads();
  float ss = 0.f, sq2 = 0.f;
#pragma unroll
  for (int g = 0; g < 8; ++g) { ss += lsum[g][t]; sq2 += lsq[g][t]; }
  psum[blockIdx.x * 256 + t] = ss;
  psq[blockIdx.x * 256 + t] = sq2;
}

// ---------------- sum partial slots + finalize BN coefficients (one block)
__global__ void k_sredfin(const float* __restrict__ psum, const float* __restrict__ psq,
                          const float* __restrict__ g, const float* __restrict__ b,
                          float* __restrict__ sc, float* __restrict__ sh, float invn) {
  int c = threadIdx.x;
  float s = 0.f, q = 0.f;
  for (int i = 0; i < SBLK; ++i) { s += psum[i * 256 + c]; q += psq[i * 256 + c]; }
  float m = s * invn;
  float v = q * invn - m * m;
  float sca = g[c] * rsqrtf(v + EPS_BN);
  sc[c] = sca;
  sh[c] = b[c] - m * sca;
}

// ---------------- y bf16 NHWC -> BN+ReLU -> padded NHWC bf16 (interior only)
__global__ void k_normalize(const bf16* __restrict__ y, const float* __restrict__ sc,
                            const float* __restrict__ sh, bf16* __restrict__ xp) {
  int t = threadIdx.x;
  int n = blockIdx.y;
  int px = blockIdx.x * 8 + (t >> 5);
  int c8 = (t & 31) * 8;
  const bf16* srcp = y + ((size_t)n * NPX + px) * CDIM + c8;
  union { bf16 b8[8]; us8 u; } in, outp;
  in.u = *(const us8*)srcp;
  int h = px / 36, w = px - h * 36;
#pragma unroll
  for (int i = 0; i < 8; ++i) {
    float v = (float)in.b8[i];
    outp.b8[i] = (bf16)fmaxf(v * sc[c8 + i] + sh[c8 + i], 0.f);
  }
  *(us8*)(xp + (size_t)n * PPIX * CDIM + ((h + 1) * PW + (w + 1)) * CDIM + c8) = outp.u;
}

// ---------------- hat-function cumulative integral: H(u) = int_{-inf}^{u} max(0,1-|x|) dx
__device__ __forceinline__ float hatH(float u) {
  u = fminf(fmaxf(u, -1.f), 1.f);
  float p = u + 1.f;
  return (u < 0.f) ? 0.5f * p * p : 0.5f + u * (1.f - 0.5f * u);
}

// ---------------- PrRoI pool, direct separable form (no integral images)
__global__ __launch_bounds__(128) void k_pool(
    const bf16* __restrict__ y, const float* __restrict__ sc,
    const float* __restrict__ sh, const float* __restrict__ props,
    bf16* __restrict__ rf) {
  int roi = blockIdx.x;
  int c = blockIdx.y * 128 + threadIdx.x;
  int b = roi >> 4;
  const float* pr = props + (size_t)roi * 4;
  float x1 = pr[0] * 20.f, yy1 = pr[1] * 20.f;
  float x2 = (pr[0] + pr[2]) * 20.f, yy2 = (pr[1] + pr[3]) * 20.f;
  float bw = (x2 - x1) * 0.25f, bh = (yy2 - yy1) * 0.25f;

  float xs[5], ys[5];
#pragma unroll
  for (int j = 0; j < 5; ++j) {
    xs[j] = fminf(fmaxf(x1 + bw * j, 0.f), 35.f);
    ys[j] = fminf(fmaxf(yy1 + bh * j, 0.f), 35.f);
  }
  float wxv[4][5], wyv[4][5];
  int sx[4], sy[4];
#pragma unroll
  for (int j = 0; j < 4; ++j) {
    float a = xs[j], bb = xs[j + 1];
    int s = (int)floorf(a);
    sx[j] = s;
#pragma unroll
    for (int k = 0; k < 5; ++k) {
      float w = (float)(s + k);
      wxv[j][k] = hatH(bb - w) - hatH(a - w);
    }
    float ay = ys[j], by = ys[j + 1];
    int t = (int)floorf(ay);
    sy[j] = t;
#pragma unroll
    for (int k = 0; k < 5; ++k) {
      float w = (float)(t + k);
      wyv[j][k] = hatH(by - w) - hatH(ay - w);
    }
  }

  float s_ = sc[c], t_ = sh[c];
  const bf16* yb = y + (size_t)b * NPX * CDIM + c;
  float acc[4][4];
#pragma unroll
  for (int i = 0; i < 4; ++i)
#pragma unroll
    for (int j = 0; j < 4; ++j) acc[i][j] = 0.f;

#pragma unroll
  for (int i = 0; i < 4; ++i) {
#pragma unroll
    for (int ky = 0; ky < 5; ++ky) {
      float wy = wyv[i][ky];
      if (wy == 0.f) continue;            // block-uniform branch
      int h = sy[i] + ky; if (h > 35) h = 35;
      const bf16* rowp = yb + h * (WW * CDIM);
#pragma unroll
      for (int j = 0; j < 4; ++j) {
        float rd = 0.f;
#pragma unroll
        for (int kx = 0; kx < 5; ++kx) {
          int w = sx[j] + kx; if (w > 35) w = 35;
          float f = fmaxf((float)rowp[w * CDIM] * s_ + t_, 0.f);
          rd += wxv[j][kx] * f;
        }
        acc[i][j] += wy * rd;
      }
    }
  }

  float area = bw * bh;
  float inv = area > 1e-8f ? 1.f / area : 0.f;
  bf16 outv[16];
#pragma unroll
  for (int i = 0; i < 4; ++i)
#pragma unroll
    for (int j = 0; j < 4; ++j)
      outv[i * 4 + j] = (bf16)(acc[i][j] * inv);
  bf16* dst = rf + (size_t)roi * FCK + c * 16;
  *(us8*)(dst)     = *(us8*)&outv[0];
  *(us8*)(dst + 8) = *(us8*)&outv[8];
}

// ---------------- fc GEMM: fcp[ks][roi][o] = partial, split-K=8, MFMA, no atomics
__global__ __launch_bounds__(256) void k_fcgemm(const bf16* __restrict__ rf,
                                                const bf16* __restrict__ fw,
                                                float* __restrict__ fcp) {
  int tid = threadIdx.x, wave = tid >> 6, lane = tid & 63;
  int wo = wave >> 1, wr = wave & 1;
  int rt = blockIdx.x, ot = blockIdx.y, ks = blockIdx.z;
  int fr = lane & 15, fg = lane >> 4;
  const bf16* ap = fw + (size_t)(ot * 64 + wo * 32 + fr) * FCK + ks * 512 + fg * 8;
  const bf16* bp = rf + (size_t)(rt * 64 + wr * 32 + fr) * FCK + ks * 512 + fg * 8;
  f32x4 acc[2][2];
#pragma unroll
  for (int i = 0; i < 2; ++i)
#pragma unroll
    for (int j = 0; j < 2; ++j) acc[i][j] = f32x4{0.f, 0.f, 0.f, 0.f};
#pragma unroll 4
  for (int k = 0; k < 512; k += 32) {
    bf16x8 a0 = *(const bf16x8*)(ap + k);
    bf16x8 a1 = *(const bf16x8*)(ap + 16 * FCK + k);
    bf16x8 b0 = *(const bf16x8*)(bp + k);
    bf16x8 b1 = *(const bf16x8*)(bp + 16 * FCK + k);
    acc[0][0] = __builtin_amdgcn_mfma_f32_16x16x32_bf16(a0, b0, acc[0][0], 0, 0, 0);
    acc[0][1] = __builtin_amdgcn_mfma_f32_16x16x32_bf16(a0, b1, acc[0][1], 0, 0, 0);
    acc[1][0] = __builtin_amdgcn_mfma_f32_16x16x32_bf16(a1, b0, acc[1][0], 0, 0, 0);
    acc[1][1] = __builtin_amdgcn_mfma_f32_16x16x32_bf16(a1, b1, acc[1][1], 0, 0, 0);
  }
#pragma unroll
  for (int i = 0; i < 2; ++i)
#pragma unroll
    for (int j = 0; j < 2; ++j) {
      int o = ot * 64 + wo * 32 + i * 16 + fg * 4;
      int r = rt * 64 + wr * 32 + j * 16 + fr;
      *(f32x4*)(fcp + ((size_t)ks * NROI + r) * CDIM + o) = acc[i][j];
    }
}

// ---------------- reduce split-K slabs: fcx[r][o] = sum_ks fcp[ks][r][o]
__global__ void k_fcred(const float* __restrict__ fcp, float* __restrict__ fcx) {
  int r = blockIdx.x, o = threadIdx.x;
  float s = 0.f;
#pragma unroll
  for (int ks = 0; ks < 8; ++ks) s += fcp[((size_t)ks * NROI + r) * CDIM + o];
  fcx[(size_t)r * CDIM + o] = s;
}

// ---------------- fc BN stats + finalize, single block (replaces k_stats+k_finalize)
__global__ void k_fcstatfin(const float* __restrict__ fcx, const float* __restrict__ g,
                            const float* __restrict__ b, float* __restrict__ sc,
                            float* __restrict__ sh) {
  int c = threadIdx.x;
  float s = 0.f, q = 0.f;
  for (int r = 0; r < NROI; ++r) {
    float v = fcx[(size_t)r * CDIM + c];
    s += v; q += v * v;
  }
  float m = s * (1.f / 512.f);
  float vv = q * (1.f / 512.f) - m * m;
  float sca = g[c] * rsqrtf(vv + EPS_BN);
  sc[c] = sca;
  sh[c] = b[c] - m * sca;
}

// ---------------- fc BN + ReLU + iou head
__global__ void k_iou(const float* __restrict__ fcx, const float* __restrict__ sc,
                      const float* __restrict__ sh, const float* __restrict__ iw,
                      const float* __restrict__ ib, float* __restrict__ out) {
  __shared__ float red[4];
  int roi = blockIdx.x, t = threadIdx.x;
  float v = fcx[(size_t)roi * CDIM + t];
  v = fmaxf(v * sc[t] + sh[t], 0.f) * iw[t];
#pragma unroll
  for (int o = 32; o > 0; o >>= 1) v += __shfl_down(v, o);
  if ((t & 63) == 0) red[t >> 6] = v;
  __syncthreads();
  if (t == 0) out[roi] = red[0] + red[1] + red[2] + red[3] + ib[0];
}

extern "C" void kernel_launch(void* const* d_in, const int* in_sizes, int n_in,
                              void* d_out, int out_size, void* d_ws, size_t ws_size,
                              hipStream_t stream) {
  (void)in_sizes; (void)n_in; (void)out_size;
  const float* feat  = (const float*)d_in[0];
  const float* props = (const float*)d_in[1];
  const float* convw[3] = {(const float*)d_in[2], (const float*)d_in[6], (const float*)d_in[10]};
  const float* bng[3]   = {(const float*)d_in[4], (const float*)d_in[8], (const float*)d_in[12]};
  const float* bnb[3]   = {(const float*)d_in[5], (const float*)d_in[9], (const float*)d_in[13]};
  const float* fcw  = (const float*)d_in[14];
  const float* fcg  = (const float*)d_in[16];
  const float* fcbb = (const float*)d_in[17];
  const float* iw   = (const float*)d_in[18];
  const float* ib   = (const float*)d_in[19];
  float* out = (float*)d_out;

  char* w = (char*)d_ws;
  size_t off = 0;
  auto take = [&](size_t sz) -> char* { char* p = w + off; off += (sz + 255) & ~(size_t)255; return p; };
  const size_t SZ_XP = (size_t)NIMG * PPIX * CDIM * 2;
  const size_t SZ_YB = (size_t)NIMG * NPX * CDIM * 2;   // bf16 y
  const size_t SZ_P  = (size_t)SBLK * 256 * 4;          // partial stats (one array)
  bf16*  xp0 = (bf16*)take(SZ_XP);
  bf16*  xp1 = (bf16*)take(SZ_XP);
  bf16*  y   = (bf16*)take(SZ_YB);
  bf16*  wball = (bf16*)take((size_t)3 * NWC * 2);
  bf16*  fwb = (bf16*)take((size_t)CDIM * FCK * 2);
  bf16*  rfb = (bf16*)take((size_t)NROI * FCK * 2);
  float* fcx = (float*)take((size_t)NROI * CDIM * 4);
  float* fcp = (float*)take((size_t)8 * NROI * CDIM * 4);
  float* psum = (float*)take(SZ_P);
  float* psq  = (float*)take(SZ_P);
  float* scsh = (float*)take(8 * 256 * 4);
  if (off > ws_size) return;  // workspace too small: fail loudly

  hipMemsetAsync(xp0, 0, SZ_XP * 2, stream);            // xp0 + xp1 are contiguous

  k_prep<<<dim3((3 * NWC + CDIM * FCK + 255) / 256), 256, 0, stream>>>(
      convw[0], convw[1], convw[2], fcw, wball, fwb);
  k_convert<<<dim3(HH, NIMG), 256, 0, stream>>>(feat, xp0);

  for (int l = 0; l < 3; ++l) {
    bf16* xin = (l == 1) ? xp1 : xp0;           // conv1<-xp0, conv2<-xp1, conv3<-xp0
    bf16* wbl = wball + (size_t)l * NWC;
    k_conv<<<dim3(704), 256, 0, stream>>>(xin, wbl, y);
    k_statsb<<<dim3(SBLK), 256, 0, stream>>>(y, psum, psq);
    float* sc = scsh + l * 512; float* sh = sc + 256;
    k_sredfin<<<dim3(1), 256, 0, stream>>>(psum, psq, bng[l], bnb[l], sc, sh, 1.f / 41472.f);
    if (l < 2) {
      bf16* xo = (l == 0) ? xp1 : xp0;
      k_normalize<<<dim3(NPX / 8, NIMG), 256, 0, stream>>>(y, sc, sh, xo);
    }
  }
  float* sc3 = scsh + 2 * 512; float* sh3 = sc3 + 256;
  k_pool<<<dim3(NROI, 2), 128, 0, stream>>>(y, sc3, sh3, props, rfb);
  k_fcgemm<<<dim3(8, 4, 8), 256, 0, stream>>>(rfb, fwb, fcp);
  k_fcred<<<dim3(NROI), 256, 0, stream>>>(fcp, fcx);
  float* fsc = scsh + 3 * 512; float* fsh = fsc + 256;
  k_fcstatfin<<<dim3(1), 256, 0, stream>>>(fcx, fcg, fcbb, fsc, fsh);
  k_iou<<<dim3(NROI), 256, 0, stream>>>(fcx, fsc, fsh, iw, ib, out);
}